// Round 1
// baseline (1692.305 us; speedup 1.0000x reference)
//
#include <hip/hip_runtime.h>
#include <math.h>

#define B_ 2
#define L_ 1024
#define DM_ 1024
#define STATE_ 16
#define CONV_ 4
#define DTR_ 8
#define INNER_ 2048
#define M_ (B_*L_)        /* 2048 rows (b,l) */
#define MD_ (B_*INNER_)   /* 4096 rows (b,c) */
#define NFFT_ 513
#define NFP_ 1040         /* 2*NFFT=1026 padded to multiple of 16 */
#define NCH_ 16
#define CHL_ 64

__device__ __forceinline__ float softplusf_(float v) {
  return (v > 20.f) ? v : log1pf(expf(v));
}

// ---------------- generic fp32 tiled GEMM ----------------
// C[m,n] = sum_k A[m,k] * B'[k,n]
// BT=true : B stored (N,K) row-major (weightsT form). BT=false: B stored (K,N).
// EPI: 0 none; 1 fusion-gate epilogue; 2 residual add.
// Requires M%64==0, K%16==0 (K%4==0 for float4 loads); N guarded.
template<bool BT, int EPI>
__global__ __launch_bounds__(256) void gemm_k(
    const float* __restrict__ A, const float* __restrict__ Bm,
    float* __restrict__ C, int M, int N, int K,
    int lda, int ldb, int ldc,
    const float* __restrict__ aux0, const float* __restrict__ aux1,
    const float* __restrict__ aux2)
{
  __shared__ float As[16][68];
  __shared__ float Bs[16][68];
  const int t  = threadIdx.x;
  const int tn = t & 15, tm = t >> 4;
  const int M0 = blockIdx.y * 64, N0 = blockIdx.x * 64;
  const int lm = t >> 2;          // 0..63
  const int lk = (t & 3) * 4;     // 0,4,8,12
  float acc[4][4] = {};

  for (int k0 = 0; k0 < K; k0 += 16) {
    { // A tile 64(m) x 16(k)
      const float* p = A + (size_t)(M0 + lm) * lda + (k0 + lk);
      float4 v = *(const float4*)p;
      As[lk+0][lm] = v.x; As[lk+1][lm] = v.y; As[lk+2][lm] = v.z; As[lk+3][lm] = v.w;
    }
    if (BT) {
      float4 v = make_float4(0.f,0.f,0.f,0.f);
      if (N0 + lm < N) v = *(const float4*)(Bm + (size_t)(N0+lm)*ldb + (k0+lk));
      Bs[lk+0][lm] = v.x; Bs[lk+1][lm] = v.y; Bs[lk+2][lm] = v.z; Bs[lk+3][lm] = v.w;
    } else {
      const int kr = t >> 4;        // 0..15
      const int nc = (t & 15) * 4;  // 0..60
      const float* p = Bm + (size_t)(k0+kr)*ldb + (N0+nc);
      #pragma unroll
      for (int j=0;j<4;j++)
        Bs[kr][nc+j] = (N0+nc+j < N) ? p[j] : 0.f;
    }
    __syncthreads();
    #pragma unroll
    for (int k=0;k<16;k++) {
      float4 av = *(const float4*)&As[k][tm*4];
      float4 bv = *(const float4*)&Bs[k][tn*4];
      float a[4] = {av.x, av.y, av.z, av.w};
      float b[4] = {bv.x, bv.y, bv.z, bv.w};
      #pragma unroll
      for (int i=0;i<4;i++)
        #pragma unroll
        for (int j=0;j<4;j++)
          acc[i][j] += a[i]*b[j];
    }
    __syncthreads();
  }
  #pragma unroll
  for (int i=0;i<4;i++) {
    int m = M0 + tm*4 + i;
    #pragma unroll
    for (int j=0;j<4;j++) {
      int n = N0 + tn*4 + j;
      if (n >= N) continue;
      float v = acc[i][j];
      if (EPI == 1) {               // fusion gate: aux0=fusion_b, aux1=y_cat, aux2=xz
        float g  = 1.f/(1.f+expf(-(v + aux0[n])));
        float ys = aux1[(size_t)m*4096 + n];
        float yp = aux1[(size_t)m*4096 + 2048 + n];
        float zv = aux2[(size_t)m*4096 + 2048 + n];
        float zs = zv/(1.f+expf(-zv));
        v = (g*ys + (1.f-g)*yp)*zs;
      } else if (EPI == 2) {        // residual add: aux0 = x (ld == ldc)
        v += aux0[(size_t)m*ldc + n];
      }
      C[(size_t)m*ldc + n] = v;
    }
  }
}

// ---------------- depthwise causal conv(4) + silu ----------------
__global__ __launch_bounds__(256) void conv_silu_k(
    const float* __restrict__ xz, const float* __restrict__ cw,
    const float* __restrict__ cb, float* __restrict__ xc)
{
  int idx = blockIdx.x*256 + threadIdx.x;
  int c = idx & (INNER_-1);
  int m = idx >> 11;
  int l = m & (L_-1);
  const float* base = xz + (size_t)m*4096 + c;
  float w0=cw[c*4+0], w1=cw[c*4+1], w2=cw[c*4+2], w3=cw[c*4+3];
  float s = cb[c] + w3*base[0];
  if (l >= 1) s += w2*base[-4096];
  if (l >= 2) s += w1*base[-2*4096];
  if (l >= 3) s += w0*base[-3*4096];
  xc[(size_t)m*INNER_ + c] = s/(1.f+expf(-s));
}

// ---------------- SSM chunked scan ----------------
// pass A: per-(b,e,chunk) local scan from h=0 -> stores P (=exp(A*sum dt)) and q
__global__ __launch_bounds__(256) void scan1_k(
    const float* __restrict__ xdbc, const float* __restrict__ xconv,
    const float* __restrict__ A_log, const float* __restrict__ dtw,
    const float* __restrict__ dtb, float* __restrict__ Pq)
{
  int idx = blockIdx.x*256 + threadIdx.x;   // (b*NCH+ch)*INNER + e
  int e  = idx & (INNER_-1);
  int bc = idx >> 11;
  int ch = bc & (NCH_-1);
  int b  = bc >> 4;
  float A[STATE_];
  #pragma unroll
  for (int s=0;s<STATE_;s++) A[s] = -expf(A_log[e*STATE_+s]);
  float w[DTR_];
  #pragma unroll
  for (int r=0;r<DTR_;r++) w[r] = dtw[e*DTR_+r];
  float bias = dtb[e];
  float h[STATE_] = {};
  float sdt = 0.f;
  int mbase = b*L_ + ch*CHL_;
  for (int l=0;l<CHL_;l++) {
    int m = mbase + l;
    const float* row = xdbc + (size_t)m*40;
    float v = bias;
    #pragma unroll
    for (int r=0;r<DTR_;r++) v += row[r]*w[r];
    float dt = softplusf_(v);
    sdt += dt;
    float dx = dt * xconv[(size_t)m*INNER_ + e];
    #pragma unroll
    for (int s=0;s<STATE_;s++) {
      float dA = expf(dt*A[s]);
      h[s] = dA*h[s] + dx*row[8+s];
    }
  }
  float* o = Pq + (size_t)idx*32;
  #pragma unroll
  for (int s=0;s<STATE_;s++) { o[s] = expf(A[s]*sdt); o[16+s] = h[s]; }
}

// pass B: serial combine of 16 chunks per (b,e); stores h_in per chunk
__global__ __launch_bounds__(256) void scan2_k(const float* __restrict__ Pq,
                                               float* __restrict__ hin)
{
  int idx = blockIdx.x*256 + threadIdx.x; // b*INNER + e  (4096 total)
  int e = idx & (INNER_-1);
  int b = idx >> 11;
  float h[STATE_] = {};
  for (int ch=0; ch<NCH_; ch++) {
    size_t tix = ((size_t)(b*NCH_+ch)*INNER_ + e);
    float* o = hin + tix*16;
    const float* pq = Pq + tix*32;
    #pragma unroll
    for (int s=0;s<STATE_;s++) o[s] = h[s];
    #pragma unroll
    for (int s=0;s<STATE_;s++) h[s] = pq[s]*h[s] + pq[16+s];
  }
}

// pass C: replay local scan with correct seed, emit y_ssm into y_cat left half
__global__ __launch_bounds__(256) void scan3_k(
    const float* __restrict__ xdbc, const float* __restrict__ xconv,
    const float* __restrict__ A_log, const float* __restrict__ dtw,
    const float* __restrict__ dtb, const float* __restrict__ Dp,
    const float* __restrict__ hin, float* __restrict__ ycat)
{
  int idx = blockIdx.x*256 + threadIdx.x;
  int e  = idx & (INNER_-1);
  int bc = idx >> 11;
  int ch = bc & (NCH_-1);
  int b  = bc >> 4;
  float A[STATE_];
  #pragma unroll
  for (int s=0;s<STATE_;s++) A[s] = -expf(A_log[e*STATE_+s]);
  float w[DTR_];
  #pragma unroll
  for (int r=0;r<DTR_;r++) w[r] = dtw[e*DTR_+r];
  float bias = dtb[e];
  float Dv = Dp[e];
  float h[STATE_];
  const float* hi = hin + (size_t)idx*16;
  #pragma unroll
  for (int s=0;s<STATE_;s++) h[s] = hi[s];
  int mbase = b*L_ + ch*CHL_;
  for (int l=0;l<CHL_;l++) {
    int m = mbase + l;
    const float* row = xdbc + (size_t)m*40;
    float v = bias;
    #pragma unroll
    for (int r=0;r<DTR_;r++) v += row[r]*w[r];
    float dt = softplusf_(v);
    float xcv = xconv[(size_t)m*INNER_ + e];
    float dx = dt * xcv;
    float y = 0.f;
    #pragma unroll
    for (int s=0;s<STATE_;s++) {
      float dA = expf(dt*A[s]);
      h[s] = dA*h[s] + dx*row[8+s];
      y += h[s]*row[24+s];
    }
    ycat[(size_t)m*4096 + e] = y + xcv*Dv;
  }
}

// ---------------- transposes ----------------
__global__ __launch_bounds__(256) void transpose_fwd_k(const float* __restrict__ xz,
                                                       float* __restrict__ xt)
{
  __shared__ float tile[32][33];
  int tx = threadIdx.x & 31, ty = threadIdx.x >> 5;
  int l0 = blockIdx.x*32, c0 = blockIdx.y*32, b = blockIdx.z;
  #pragma unroll
  for (int j=0;j<4;j++) {
    int l = l0 + ty + j*8;
    tile[ty+j*8][tx] = xz[(size_t)(b*L_+l)*4096 + (c0+tx)];
  }
  __syncthreads();
  #pragma unroll
  for (int j=0;j<4;j++) {
    int c = c0 + ty + j*8;
    xt[(size_t)(b*INNER_+c)*L_ + (l0+tx)] = tile[tx][ty+j*8];
  }
}

__global__ __launch_bounds__(256) void transpose_bwd_k(const float* __restrict__ yt,
                                                       float* __restrict__ ycat)
{
  __shared__ float tile[32][33];
  int tx = threadIdx.x & 31, ty = threadIdx.x >> 5;
  int l0 = blockIdx.x*32, c0 = blockIdx.y*32, b = blockIdx.z;
  #pragma unroll
  for (int j=0;j<4;j++) {
    int c = c0 + ty + j*8;
    tile[ty+j*8][tx] = yt[(size_t)(b*INNER_+c)*L_ + (l0+tx)];
  }
  __syncthreads();
  #pragma unroll
  for (int j=0;j<4;j++) {
    int l = l0 + ty + j*8;
    ycat[(size_t)(b*L_+l)*4096 + 2048 + (c0+tx)] = tile[tx][ty+j*8];
  }
}

// ---------------- DFT matrix generation ----------------
__global__ __launch_bounds__(256) void genWdft_k(float* __restrict__ W) {
  int idx = blockIdx.x*256 + threadIdx.x;  // l*NFP_ + col
  int col = idx % NFP_;
  int l = idx / NFP_;
  float v = 0.f;
  int f = col >> 1;
  if (f < NFFT_) {
    int ph = (l*f) & (L_-1);
    float th = (float)ph * (6.283185307179586f / (float)L_);
    v = (col & 1) ? -sinf(th) : cosf(th);
  }
  W[idx] = v;
}

__global__ __launch_bounds__(256) void genWinv_k(float* __restrict__ W) {
  int idx = blockIdx.x*256 + threadIdx.x;  // r*1024 + l
  int l = idx & (L_-1);
  int r = idx >> 10;
  int f = r >> 1;
  float v = 0.f;
  if (f < NFFT_) {
    bool edge = (f == 0) || (f == 512);
    float sc = (edge ? 1.f : 2.f) / (float)L_;
    int ph = (f*l) & (L_-1);
    float th = (float)ph * (6.283185307179586f / (float)L_);
    if (r & 1) v = edge ? 0.f : -sc*sinf(th);
    else       v = sc*cosf(th);
  }
  W[idx] = v;
}

// ---------------- pointwise spectral filter ----------------
__global__ __launch_bounds__(256) void filtmul_k(float* __restrict__ XF,
    const float* __restrict__ fr, const float* __restrict__ fi,
    const float* __restrict__ dec)
{
  int idx = blockIdx.x*256 + threadIdx.x;
  if (idx >= MD_*NFFT_) return;
  int f  = idx % NFFT_;
  int mc = idx / NFFT_;
  int c  = mc & (INNER_-1);
  float d  = expf(-dec[c] * (float)f * (1.f/512.f));
  float wr = fr[c*NFFT_+f]*d, wi = fi[c*NFFT_+f]*d;
  size_t p = (size_t)mc*NFP_ + 2*f;
  float a = XF[p], bb = XF[p+1];
  XF[p]   = a*wr - bb*wi;
  XF[p+1] = a*wi + bb*wr;
}

// ---------------- layernorm ----------------
__global__ __launch_bounds__(256) void ln_k(const float* __restrict__ inp,
    const float* __restrict__ gma, const float* __restrict__ bta,
    float* __restrict__ out)
{
  int m = blockIdx.x;
  const float* row = inp + (size_t)m*DM_;
  float s=0.f, s2=0.f;
  float v[4];
  #pragma unroll
  for (int j=0;j<4;j++) {
    v[j] = row[threadIdx.x + j*256];
    s += v[j]; s2 += v[j]*v[j];
  }
  #pragma unroll
  for (int off=32; off>=1; off>>=1) {
    s  += __shfl_down(s, off);
    s2 += __shfl_down(s2, off);
  }
  __shared__ float rs[4], rs2[4], stats[2];
  int wid = threadIdx.x >> 6;
  if ((threadIdx.x & 63) == 0) { rs[wid]=s; rs2[wid]=s2; }
  __syncthreads();
  if (threadIdx.x == 0) {
    float ts  = rs[0]+rs[1]+rs[2]+rs[3];
    float ts2 = rs2[0]+rs2[1]+rs2[2]+rs2[3];
    float mu  = ts/(float)DM_;
    float var = ts2/(float)DM_ - mu*mu;
    stats[0] = mu; stats[1] = rsqrtf(var + 1e-5f);
  }
  __syncthreads();
  float mu = stats[0], rstd = stats[1];
  #pragma unroll
  for (int j=0;j<4;j++) {
    int n = threadIdx.x + j*256;
    out[(size_t)m*DM_ + n] = (v[j]-mu)*rstd*gma[n] + bta[n];
  }
}

extern "C" void kernel_launch(void* const* d_in, const int* in_sizes, int n_in,
                              void* d_out, int out_size, void* d_ws, size_t ws_size,
                              hipStream_t stream)
{
  const float* x       = (const float*)d_in[0];
  const float* in_w    = (const float*)d_in[1];
  const float* conv_w  = (const float*)d_in[2];
  const float* conv_b  = (const float*)d_in[3];
  const float* A_log   = (const float*)d_in[4];
  const float* Dp      = (const float*)d_in[5];
  const float* xproj_w = (const float*)d_in[6];
  const float* dt_w    = (const float*)d_in[7];
  const float* dt_b    = (const float*)d_in[8];
  const float* f_re    = (const float*)d_in[9];
  const float* f_im    = (const float*)d_in[10];
  const float* s_dec   = (const float*)d_in[11];
  const float* fus_w   = (const float*)d_in[12];
  const float* fus_b   = (const float*)d_in[13];
  const float* out_w   = (const float*)d_in[14];
  const float* ln_g    = (const float*)d_in[15];
  const float* ln_b    = (const float*)d_in[16];
  float* out = (float*)d_out;

  // workspace layout (floats); total ~34.8M floats (~139 MB)
  float* ws    = (float*)d_ws;
  float* xz    = ws;                       // 8388608  (M x 4096)
  float* xconv = xz    + 8388608;          // 4194304  (M x 2048)
  float* xdbc  = xconv + 4194304;          // 81920    (M x 40)
  float* Pq    = xdbc  + 81920;            // 2097152
  float* hin   = Pq    + 2097152;          // 1048576
  float* xt    = hin   + 1048576;          // 4194304  (MD x 1024) reused as y_t
  float* Wdft  = xt    + 4194304;          // 1064960  (1024 x NFP)
  float* XF    = Wdft  + 1064960;          // 4259840  (MD x NFP) reused as y_comb
  float* Winv  = XF    + 4259840;          // 1064960  (NFP x 1024)
  float* ycat  = Winv  + 1064960;          // 8388608  (M x 4096)
  float* yt    = xt;
  float* ycomb = XF;
  float* outp  = xconv;                    // reuse after scan3

  // 1. xz = x @ in_proj_w^T       (2048 x 4096 x 1024)
  gemm_k<true,0><<<dim3(4096/64, M_/64), 256, 0, stream>>>(
      x, in_w, xz, M_, 4096, 1024, 1024, 1024, 4096, nullptr, nullptr, nullptr);
  // 2. depthwise conv + silu
  conv_silu_k<<<(M_*INNER_)/256, 256, 0, stream>>>(xz, conv_w, conv_b, xconv);
  // 3. x_dbc = x_conv @ x_proj_w^T  (2048 x 40 x 2048)
  gemm_k<true,0><<<dim3(1, M_/64), 256, 0, stream>>>(
      xconv, xproj_w, xdbc, M_, 40, 2048, 2048, 2048, 40, nullptr, nullptr, nullptr);
  // 4-6. chunked SSM scan -> y_cat[:, :2048]
  scan1_k<<<(B_*NCH_*INNER_)/256, 256, 0, stream>>>(xdbc, xconv, A_log, dt_w, dt_b, Pq);
  scan2_k<<<MD_/256, 256, 0, stream>>>(Pq, hin);
  scan3_k<<<(B_*NCH_*INNER_)/256, 256, 0, stream>>>(xdbc, xconv, A_log, dt_w, dt_b, Dp, hin, ycat);
  // 7. transpose x_inner -> (b,c,l)
  transpose_fwd_k<<<dim3(L_/32, INNER_/32, B_), 256, 0, stream>>>(xz, xt);
  // 8-9. forward DFT: XF = xt @ Wdft  (4096 x 1040 x 1024)
  genWdft_k<<<(1024*NFP_)/256, 256, 0, stream>>>(Wdft);
  gemm_k<false,0><<<dim3((NFP_+63)/64, MD_/64), 256, 0, stream>>>(
      xt, Wdft, XF, MD_, NFP_, 1024, 1024, NFP_, NFP_, nullptr, nullptr, nullptr);
  // 10. spectral filter (in place)
  filtmul_k<<<(MD_*NFFT_+255)/256, 256, 0, stream>>>(XF, f_re, f_im, s_dec);
  // 11-12. inverse DFT: y_t = XF @ Winv  (4096 x 1024 x 1040)
  genWinv_k<<<(NFP_*1024)/256, 256, 0, stream>>>(Winv);
  gemm_k<false,0><<<dim3(1024/64, MD_/64), 256, 0, stream>>>(
      XF, Winv, yt, MD_, 1024, NFP_, NFP_, 1024, 1024, nullptr, nullptr, nullptr);
  // 13. transpose back -> y_cat[:, 2048:]
  transpose_bwd_k<<<dim3(L_/32, INNER_/32, B_), 256, 0, stream>>>(yt, ycat);
  // 14. fusion GEMM + gate epilogue  (2048 x 2048 x 4096)
  gemm_k<true,1><<<dim3(2048/64, M_/64), 256, 0, stream>>>(
      ycat, fus_w, ycomb, M_, 2048, 4096, 4096, 4096, 2048, fus_b, ycat, xz);
  // 15. out proj + residual         (2048 x 1024 x 2048)
  gemm_k<true,2><<<dim3(1024/64, M_/64), 256, 0, stream>>>(
      ycomb, out_w, outp, M_, 1024, 2048, 2048, 2048, 1024, x, nullptr, nullptr);
  // 16. layernorm -> d_out
  ln_k<<<M_, 256, 0, stream>>>(outp, ln_g, ln_b, out);
}

// Round 2
// 715.441 us; speedup vs baseline: 2.3654x; 2.3654x over previous
//
#include <hip/hip_runtime.h>
#include <math.h>

#define B_ 2
#define L_ 1024
#define DM_ 1024
#define STATE_ 16
#define CONV_ 4
#define DTR_ 8
#define INNER_ 2048
#define M_ (B_*L_)        /* 2048 rows (b,l) */
#define MD_ (B_*INNER_)   /* 4096 rows (b,c) */
#define NFFT_ 513
#define NFP_ 1152         /* 2*513=1026 padded to multiple of 128 */
#define NCH_ 16
#define CHL_ 64

typedef unsigned short u16;
typedef __attribute__((ext_vector_type(8))) short short8;
typedef __attribute__((ext_vector_type(8))) __bf16 bf16x8;
typedef __attribute__((ext_vector_type(4))) float f32x4;

__device__ __forceinline__ float softplusf_(float v) {
  return (v > 20.f) ? v : log1pf(expf(v));
}
__device__ __forceinline__ u16 f2bf(float f) {
  union { float f; unsigned u; } v; v.f = f;
  unsigned r = v.u + 0x7fffu + ((v.u >> 16) & 1u);
  return (u16)(r >> 16);
}
__device__ __forceinline__ float bf2f(u16 h) {
  union { unsigned u; float f; } v; v.u = ((unsigned)h) << 16;
  return v.f;
}
__device__ __forceinline__ void gload16(const void* g, void* l) {
  __builtin_amdgcn_global_load_lds(
      (const __attribute__((address_space(1))) unsigned*)g,
      (__attribute__((address_space(3))) unsigned*)l, 16, 0, 0);
}
__device__ __forceinline__ f32x4 mfma_bf16(short8 a, short8 b, f32x4 c) {
  return __builtin_amdgcn_mfma_f32_16x16x32_bf16(
      __builtin_bit_cast(bf16x8, a), __builtin_bit_cast(bf16x8, b), c, 0, 0, 0);
}

// ---------------- fp32 -> bf16 conversion ----------------
__global__ __launch_bounds__(256) void cvt_k(const float* __restrict__ in,
                                             u16* __restrict__ out) {
  int i = (blockIdx.x*256 + threadIdx.x) * 4;
  float4 v = *(const float4*)(in + i);
  ushort4 o;
  o.x = f2bf(v.x); o.y = f2bf(v.y); o.z = f2bf(v.z); o.w = f2bf(v.w);
  *(ushort4*)(out + i) = o;
}

// ---------------- bf16 MFMA GEMM ----------------
// C[m,n] = sum_k A[m,k]*Bt[n,k].  A: M x K bf16, Bt: N x K bf16, K%64==0,
// M%128==0, N%128==0. Block: 512 thr (8 waves), tile 128x128, BK=64.
// EPI: 0 plain f32 out; 1 fusion gate (bf16 out); 2 residual add (f32 out);
//      3 spectral filter (bf16 out); 4 plain bf16 out.
template<int EPI>
__global__ __launch_bounds__(512) void mgemm_k(
    const u16* __restrict__ Ab, const u16* __restrict__ Bb,
    void* __restrict__ Cout, int K, int ldc,
    const float* __restrict__ aux0, const u16* __restrict__ aux1,
    const float* __restrict__ aux2, const float* __restrict__ aux3)
{
  __shared__ __align__(16) u16 As[128*64];
  __shared__ __align__(16) u16 Bs[128*64];
  const int t = threadIdx.x;
  const int lane = t & 63;
  const int w = t >> 6;                 // 0..7
  const int wm = w >> 2, wn = w & 3;    // wave sub-tile: rows 64*wm, cols 32*wn
  const int M0 = blockIdx.y * 128, N0 = blockIdx.x * 128;

  f32x4 acc[4][2] = {};

  for (int k0 = 0; k0 < K; k0 += 64) {
    #pragma unroll
    for (int q = 0; q < 2; q++) {       // A tile: 1024 16B-units
      int u = q*512 + t;
      int row = u >> 3, gpr = u & 7;
      int grp = gpr ^ (row & 7);        // XOR swizzle
      gload16(Ab + (size_t)(M0+row)*K + k0 + grp*8, &As[u*8]);
    }
    #pragma unroll
    for (int q = 0; q < 2; q++) {       // B tile
      int u = q*512 + t;
      int row = u >> 3, gpr = u & 7;
      int grp = gpr ^ (row & 7);
      gload16(Bb + (size_t)(N0+row)*K + k0 + grp*8, &Bs[u*8]);
    }
    __syncthreads();
    #pragma unroll
    for (int kk = 0; kk < 2; kk++) {
      const int quad = lane >> 4;
      const int grp = kk*4 + quad;
      short8 af[4], bf[2];
      #pragma unroll
      for (int i = 0; i < 4; i++) {
        int row = wm*64 + i*16 + (lane & 15);
        af[i] = *(const short8*)&As[(row*8 + (grp ^ (row & 7)))*8];
      }
      #pragma unroll
      for (int j = 0; j < 2; j++) {
        int row = wn*32 + j*16 + (lane & 15);
        bf[j] = *(const short8*)&Bs[(row*8 + (grp ^ (row & 7)))*8];
      }
      #pragma unroll
      for (int i = 0; i < 4; i++)
        #pragma unroll
        for (int j = 0; j < 2; j++)
          acc[i][j] = mfma_bf16(af[i], bf[j], acc[i][j]);
    }
    __syncthreads();
  }

  // C/D layout: col = lane&15, row = (lane>>4)*4 + r
  #pragma unroll
  for (int i = 0; i < 4; i++) {
    int mbase = M0 + wm*64 + i*16 + (lane >> 4)*4;
    #pragma unroll
    for (int j = 0; j < 2; j++) {
      int n = N0 + wn*32 + j*16 + (lane & 15);
      #pragma unroll
      for (int r = 0; r < 4; r++) {
        int m = mbase + r;
        float v = acc[i][j][r];
        if (EPI == 0) {
          ((float*)Cout)[(size_t)m*ldc + n] = v;
        } else if (EPI == 1) {          // fusion gate
          float g  = 1.f/(1.f+expf(-(v + aux0[n])));
          float ys = bf2f(aux1[(size_t)m*4096 + n]);
          float yp = bf2f(aux1[(size_t)m*4096 + 2048 + n]);
          float z  = aux2[(size_t)m*4096 + 2048 + n];
          float zs = z/(1.f+expf(-z));
          ((u16*)Cout)[(size_t)m*ldc + n] = f2bf((g*ys + (1.f-g)*yp)*zs);
        } else if (EPI == 2) {          // residual add
          ((float*)Cout)[(size_t)m*ldc + n] = v + aux2[(size_t)m*ldc + n];
        } else if (EPI == 3) {          // spectral filter, complex pair via shfl
          float pv = __shfl_xor(v, 1, 64);
          int f = n >> 1;
          float outv = 0.f;
          if (f < NFFT_) {
            int c = m & (INNER_-1);
            float d  = expf(-aux2[c] * (float)f * (1.f/512.f));
            float wr = aux0[c*NFFT_+f]*d, wi = aux3[c*NFFT_+f]*d;
            float a = (n & 1) ? pv : v;
            float b = (n & 1) ? v : pv;
            outv = (n & 1) ? (a*wi + b*wr) : (a*wr - b*wi);
          }
          ((u16*)Cout)[(size_t)m*ldc + n] = f2bf(outv);
        } else {                        // 4: plain bf16
          ((u16*)Cout)[(size_t)m*ldc + n] = f2bf(v);
        }
      }
    }
  }
}

// ---------------- fp32 tiled GEMM (x_proj only, N=40) ----------------
template<bool BT, int EPI>
__global__ __launch_bounds__(256) void gemm_k(
    const float* __restrict__ A, const float* __restrict__ Bm,
    float* __restrict__ C, int M, int N, int K,
    int lda, int ldb, int ldc,
    const float* __restrict__ aux0, const float* __restrict__ aux1,
    const float* __restrict__ aux2)
{
  __shared__ float As[16][68];
  __shared__ float Bs[16][68];
  const int t  = threadIdx.x;
  const int tn = t & 15, tm = t >> 4;
  const int M0 = blockIdx.y * 64, N0 = blockIdx.x * 64;
  const int lm = t >> 2;
  const int lk = (t & 3) * 4;
  float acc[4][4] = {};

  for (int k0 = 0; k0 < K; k0 += 16) {
    {
      const float* p = A + (size_t)(M0 + lm) * lda + (k0 + lk);
      float4 v = *(const float4*)p;
      As[lk+0][lm] = v.x; As[lk+1][lm] = v.y; As[lk+2][lm] = v.z; As[lk+3][lm] = v.w;
    }
    {
      float4 v = make_float4(0.f,0.f,0.f,0.f);
      if (N0 + lm < N) v = *(const float4*)(Bm + (size_t)(N0+lm)*ldb + (k0+lk));
      Bs[lk+0][lm] = v.x; Bs[lk+1][lm] = v.y; Bs[lk+2][lm] = v.z; Bs[lk+3][lm] = v.w;
    }
    __syncthreads();
    #pragma unroll
    for (int k=0;k<16;k++) {
      float4 av = *(const float4*)&As[k][tm*4];
      float4 bv = *(const float4*)&Bs[k][tn*4];
      float a[4] = {av.x, av.y, av.z, av.w};
      float b[4] = {bv.x, bv.y, bv.z, bv.w};
      #pragma unroll
      for (int i=0;i<4;i++)
        #pragma unroll
        for (int j=0;j<4;j++)
          acc[i][j] += a[i]*b[j];
    }
    __syncthreads();
  }
  #pragma unroll
  for (int i=0;i<4;i++) {
    int m = M0 + tm*4 + i;
    #pragma unroll
    for (int j=0;j<4;j++) {
      int n = N0 + tn*4 + j;
      if (n >= N) continue;
      C[(size_t)m*ldc + n] = acc[i][j];
    }
  }
}

// ---------------- depthwise causal conv(4) + silu ----------------
__global__ __launch_bounds__(256) void conv_silu_k(
    const float* __restrict__ xz, const float* __restrict__ cw,
    const float* __restrict__ cb, float* __restrict__ xc)
{
  int idx = blockIdx.x*256 + threadIdx.x;
  int c = idx & (INNER_-1);
  int m = idx >> 11;
  int l = m & (L_-1);
  const float* base = xz + (size_t)m*4096 + c;
  float w0=cw[c*4+0], w1=cw[c*4+1], w2=cw[c*4+2], w3=cw[c*4+3];
  float s = cb[c] + w3*base[0];
  if (l >= 1) s += w2*base[-4096];
  if (l >= 2) s += w1*base[-2*4096];
  if (l >= 3) s += w0*base[-3*4096];
  xc[(size_t)m*INNER_ + c] = s/(1.f+expf(-s));
}

// ---------------- SSM chunked scan ----------------
__global__ __launch_bounds__(256) void scan1_k(
    const float* __restrict__ xdbc, const float* __restrict__ xconv,
    const float* __restrict__ A_log, const float* __restrict__ dtw,
    const float* __restrict__ dtb, float* __restrict__ Pq)
{
  int idx = blockIdx.x*256 + threadIdx.x;
  int e  = idx & (INNER_-1);
  int bc = idx >> 11;
  int ch = bc & (NCH_-1);
  int b  = bc >> 4;
  float A[STATE_];
  #pragma unroll
  for (int s=0;s<STATE_;s++) A[s] = -expf(A_log[e*STATE_+s]);
  float w[DTR_];
  #pragma unroll
  for (int r=0;r<DTR_;r++) w[r] = dtw[e*DTR_+r];
  float bias = dtb[e];
  float h[STATE_] = {};
  float sdt = 0.f;
  int mbase = b*L_ + ch*CHL_;
  for (int l=0;l<CHL_;l++) {
    int m = mbase + l;
    const float* row = xdbc + (size_t)m*40;
    float v = bias;
    #pragma unroll
    for (int r=0;r<DTR_;r++) v += row[r]*w[r];
    float dt = softplusf_(v);
    sdt += dt;
    float dx = dt * xconv[(size_t)m*INNER_ + e];
    #pragma unroll
    for (int s=0;s<STATE_;s++) {
      float dA = expf(dt*A[s]);
      h[s] = dA*h[s] + dx*row[8+s];
    }
  }
  float* o = Pq + (size_t)idx*32;
  #pragma unroll
  for (int s=0;s<STATE_;s++) { o[s] = expf(A[s]*sdt); o[16+s] = h[s]; }
}

__global__ __launch_bounds__(256) void scan2_k(const float* __restrict__ Pq,
                                               float* __restrict__ hin)
{
  int idx = blockIdx.x*256 + threadIdx.x;
  int e = idx & (INNER_-1);
  int b = idx >> 11;
  float h[STATE_] = {};
  for (int ch=0; ch<NCH_; ch++) {
    size_t tix = ((size_t)(b*NCH_+ch)*INNER_ + e);
    float* o = hin + tix*16;
    const float* pq = Pq + tix*32;
    #pragma unroll
    for (int s=0;s<STATE_;s++) o[s] = h[s];
    #pragma unroll
    for (int s=0;s<STATE_;s++) h[s] = pq[s]*h[s] + pq[16+s];
  }
}

__global__ __launch_bounds__(256) void scan3_k(
    const float* __restrict__ xdbc, const float* __restrict__ xconv,
    const float* __restrict__ A_log, const float* __restrict__ dtw,
    const float* __restrict__ dtb, const float* __restrict__ Dp,
    const float* __restrict__ hin, u16* __restrict__ ycat)
{
  int idx = blockIdx.x*256 + threadIdx.x;
  int e  = idx & (INNER_-1);
  int bc = idx >> 11;
  int ch = bc & (NCH_-1);
  int b  = bc >> 4;
  float A[STATE_];
  #pragma unroll
  for (int s=0;s<STATE_;s++) A[s] = -expf(A_log[e*STATE_+s]);
  float w[DTR_];
  #pragma unroll
  for (int r=0;r<DTR_;r++) w[r] = dtw[e*DTR_+r];
  float bias = dtb[e];
  float Dv = Dp[e];
  float h[STATE_];
  const float* hi = hin + (size_t)idx*16;
  #pragma unroll
  for (int s=0;s<STATE_;s++) h[s] = hi[s];
  int mbase = b*L_ + ch*CHL_;
  for (int l=0;l<CHL_;l++) {
    int m = mbase + l;
    const float* row = xdbc + (size_t)m*40;
    float v = bias;
    #pragma unroll
    for (int r=0;r<DTR_;r++) v += row[r]*w[r];
    float dt = softplusf_(v);
    float xcv = xconv[(size_t)m*INNER_ + e];
    float dx = dt * xcv;
    float y = 0.f;
    #pragma unroll
    for (int s=0;s<STATE_;s++) {
      float dA = expf(dt*A[s]);
      h[s] = dA*h[s] + dx*row[8+s];
      y += h[s]*row[24+s];
    }
    ycat[(size_t)m*4096 + e] = f2bf(y + xcv*Dv);
  }
}

// ---------------- transposes ----------------
__global__ __launch_bounds__(256) void transpose_fwd_k(const float* __restrict__ xz,
                                                       u16* __restrict__ xt)
{
  __shared__ float tile[32][33];
  int tx = threadIdx.x & 31, ty = threadIdx.x >> 5;
  int l0 = blockIdx.x*32, c0 = blockIdx.y*32, b = blockIdx.z;
  #pragma unroll
  for (int j=0;j<4;j++) {
    int l = l0 + ty + j*8;
    tile[ty+j*8][tx] = xz[(size_t)(b*L_+l)*4096 + (c0+tx)];
  }
  __syncthreads();
  #pragma unroll
  for (int j=0;j<4;j++) {
    int c = c0 + ty + j*8;
    xt[(size_t)(b*INNER_+c)*L_ + (l0+tx)] = f2bf(tile[tx][ty+j*8]);
  }
}

__global__ __launch_bounds__(256) void transpose_bwd_k(const u16* __restrict__ yt,
                                                       u16* __restrict__ ycat)
{
  __shared__ float tile[32][33];
  int tx = threadIdx.x & 31, ty = threadIdx.x >> 5;
  int l0 = blockIdx.x*32, c0 = blockIdx.y*32, b = blockIdx.z;
  #pragma unroll
  for (int j=0;j<4;j++) {
    int c = c0 + ty + j*8;
    tile[ty+j*8][tx] = bf2f(yt[(size_t)(b*INNER_+c)*L_ + (l0+tx)]);
  }
  __syncthreads();
  #pragma unroll
  for (int j=0;j<4;j++) {
    int l = l0 + ty + j*8;
    ycat[(size_t)(b*L_+l)*4096 + 2048 + (c0+tx)] = f2bf(tile[tx][ty+j*8]);
  }
}

// ---------------- DFT matrix generation (bf16, K-contiguous) ----------------
__global__ __launch_bounds__(256) void genWdftb_k(u16* __restrict__ W) {
  int idx = blockIdx.x*256 + threadIdx.x;  // col*1024 + l ; col < NFP_
  int l = idx & (L_-1);
  int col = idx >> 10;
  float v = 0.f;
  int f = col >> 1;
  if (f < NFFT_) {
    int ph = (l*f) & (L_-1);
    float th = (float)ph * (6.283185307179586f / (float)L_);
    v = (col & 1) ? -sinf(th) : cosf(th);
  }
  W[idx] = f2bf(v);
}

__global__ __launch_bounds__(256) void genWinvb_k(u16* __restrict__ W) {
  int idx = blockIdx.x*256 + threadIdx.x;  // l*NFP_ + r
  int r = idx % NFP_;
  int l = idx / NFP_;
  int f = r >> 1;
  float v = 0.f;
  if (f < NFFT_) {
    bool edge = (f == 0) || (f == 512);
    float sc = (edge ? 1.f : 2.f) / (float)L_;
    int ph = (f*l) & (L_-1);
    float th = (float)ph * (6.283185307179586f / (float)L_);
    if (r & 1) v = edge ? 0.f : -sc*sinf(th);
    else       v = sc*cosf(th);
  }
  W[idx] = f2bf(v);
}

// ---------------- layernorm ----------------
__global__ __launch_bounds__(256) void ln_k(const float* __restrict__ inp,
    const float* __restrict__ gma, const float* __restrict__ bta,
    float* __restrict__ out)
{
  int m = blockIdx.x;
  const float* row = inp + (size_t)m*DM_;
  float s=0.f, s2=0.f;
  float v[4];
  #pragma unroll
  for (int j=0;j<4;j++) {
    v[j] = row[threadIdx.x + j*256];
    s += v[j]; s2 += v[j]*v[j];
  }
  #pragma unroll
  for (int off=32; off>=1; off>>=1) {
    s  += __shfl_down(s, off);
    s2 += __shfl_down(s2, off);
  }
  __shared__ float rs[4], rs2[4], stats[2];
  int wid = threadIdx.x >> 6;
  if ((threadIdx.x & 63) == 0) { rs[wid]=s; rs2[wid]=s2; }
  __syncthreads();
  if (threadIdx.x == 0) {
    float ts  = rs[0]+rs[1]+rs[2]+rs[3];
    float ts2 = rs2[0]+rs2[1]+rs2[2]+rs2[3];
    float mu  = ts/(float)DM_;
    float var = ts2/(float)DM_ - mu*mu;
    stats[0] = mu; stats[1] = rsqrtf(var + 1e-5f);
  }
  __syncthreads();
  float mu = stats[0], rstd = stats[1];
  #pragma unroll
  for (int j=0;j<4;j++) {
    int n = threadIdx.x + j*256;
    out[(size_t)m*DM_ + n] = (v[j]-mu)*rstd*gma[n] + bta[n];
  }
}

extern "C" void kernel_launch(void* const* d_in, const int* in_sizes, int n_in,
                              void* d_out, int out_size, void* d_ws, size_t ws_size,
                              hipStream_t stream)
{
  const float* x       = (const float*)d_in[0];
  const float* in_w    = (const float*)d_in[1];
  const float* conv_w  = (const float*)d_in[2];
  const float* conv_b  = (const float*)d_in[3];
  const float* A_log   = (const float*)d_in[4];
  const float* Dp      = (const float*)d_in[5];
  const float* xproj_w = (const float*)d_in[6];
  const float* dt_w    = (const float*)d_in[7];
  const float* dt_b    = (const float*)d_in[8];
  const float* f_re    = (const float*)d_in[9];
  const float* f_im    = (const float*)d_in[10];
  const float* s_dec   = (const float*)d_in[11];
  const float* fus_w   = (const float*)d_in[12];
  const float* fus_b   = (const float*)d_in[13];
  const float* out_w   = (const float*)d_in[14];
  const float* ln_g    = (const float*)d_in[15];
  const float* ln_b    = (const float*)d_in[16];
  float* out = (float*)d_out;

  // ---- workspace carve (fp32 region then bf16 region), ~134 MB total ----
  float* ws    = (float*)d_ws;
  float* xz    = ws;                       // 8388608  (M x 4096)
  float* xconv = xz    + 8388608;          // 4194304  (M x 2048), reused as outp
  float* xdbc  = xconv + 4194304;          // 81920    (M x 40)
  float* Pq    = xdbc  + 81920;            // 2097152
  float* hin   = Pq    + 2097152;          // 1048576
  u16* ub      = (u16*)(hin + 1048576);
  u16* xb      = ub;                       // 2097152   x bf16
  u16* inwb    = xb    + 2097152;          // 4194304   in_w bf16; reused as yt
  u16* fuswb   = inwb  + 4194304;          // 8388608   fus_w bf16
  u16* outwb   = fuswb + 8388608;          // 2097152   out_w bf16
  u16* xt      = outwb + 2097152;          // 4194304   x_inner^T bf16; reused as ycomb
  u16* Wb      = xt    + 4194304;          // 1179648   Wdft then Winv
  u16* XFb     = Wb    + 1179648;          // 4718592   (MD x NFP) bf16
  u16* ycat    = XFb   + 4718592;          // 8388608   (M x 4096) bf16
  u16* yt      = inwb;
  u16* ycomb   = xt;
  float* outp  = xconv;

  // 0. convert GEMM operands to bf16
  cvt_k<<<2097152/1024, 256, 0, stream>>>(x, xb);
  cvt_k<<<4194304/1024, 256, 0, stream>>>(in_w, inwb);
  cvt_k<<<8388608/1024, 256, 0, stream>>>(fus_w, fuswb);
  cvt_k<<<2097152/1024, 256, 0, stream>>>(out_w, outwb);

  // 1. xz = x @ in_proj_w^T   (2048 x 4096 x 1024) MFMA
  mgemm_k<0><<<dim3(4096/128, M_/128), 512, 0, stream>>>(
      xb, inwb, xz, 1024, 4096, nullptr, nullptr, nullptr, nullptr);
  // 2. depthwise conv + silu
  conv_silu_k<<<(M_*INNER_)/256, 256, 0, stream>>>(xz, conv_w, conv_b, xconv);
  // 3. x_dbc = x_conv @ x_proj_w^T  (2048 x 40 x 2048) fp32
  gemm_k<true,0><<<dim3(1, M_/64), 256, 0, stream>>>(
      xconv, xproj_w, xdbc, M_, 40, 2048, 2048, 2048, 40, nullptr, nullptr, nullptr);
  // 4-6. chunked SSM scan -> y_cat[:, :2048] (bf16)
  scan1_k<<<(B_*NCH_*INNER_)/256, 256, 0, stream>>>(xdbc, xconv, A_log, dt_w, dt_b, Pq);
  scan2_k<<<MD_/256, 256, 0, stream>>>(Pq, hin);
  scan3_k<<<(B_*NCH_*INNER_)/256, 256, 0, stream>>>(xdbc, xconv, A_log, dt_w, dt_b, Dp, hin, ycat);
  // 7. transpose x_inner -> (b,c,l) bf16
  transpose_fwd_k<<<dim3(L_/32, INNER_/32, B_), 256, 0, stream>>>(xz, xt);
  // 8. forward DFT + fused spectral filter: XFb = filt(xt @ Wdft)
  genWdftb_k<<<(NFP_*1024)/256, 256, 0, stream>>>(Wb);
  mgemm_k<3><<<dim3(NFP_/128, MD_/128), 512, 0, stream>>>(
      xt, Wb, XFb, 1024, NFP_, f_re, nullptr, s_dec, f_im);
  // 9. inverse DFT: yt = XFb @ Winv  (4096 x 1024 x 1152) -> bf16
  genWinvb_k<<<(NFP_*1024)/256, 256, 0, stream>>>(Wb);
  mgemm_k<4><<<dim3(1024/128, MD_/128), 512, 0, stream>>>(
      XFb, Wb, yt, NFP_, 1024, nullptr, nullptr, nullptr, nullptr);
  // 10. transpose back -> y_cat[:, 2048:]
  transpose_bwd_k<<<dim3(L_/32, INNER_/32, B_), 256, 0, stream>>>(yt, ycat);
  // 11. fusion GEMM + gate epilogue (2048 x 2048 x 4096) -> ycomb bf16
  mgemm_k<1><<<dim3(2048/128, M_/128), 512, 0, stream>>>(
      ycat, fuswb, ycomb, 4096, 2048, fus_b, ycat, xz, nullptr);
  // 12. out proj + residual (2048 x 1024 x 2048) -> fp32
  mgemm_k<2><<<dim3(1024/128, M_/128), 512, 0, stream>>>(
      ycomb, outwb, outp, 2048, 1024, nullptr, nullptr, x, nullptr);
  // 13. layernorm -> d_out
  ln_k<<<M_, 256, 0, stream>>>(outp, ln_g, ln_b, out);
}

// Round 3
// 620.920 us; speedup vs baseline: 2.7255x; 1.1522x over previous
//
#include <hip/hip_runtime.h>
#include <math.h>

#define B_ 2
#define L_ 1024
#define DM_ 1024
#define STATE_ 16
#define CONV_ 4
#define DTR_ 8
#define INNER_ 2048
#define M_ (B_*L_)        /* 2048 rows (b,l) */
#define MD_ (B_*INNER_)   /* 4096 rows (b,c) */
#define NFFT_ 513
#define NFP_ 1152         /* 2*513=1026 padded to multiple of 128 */
#define NCH_ 16
#define CHL_ 64
#define SK_ 32            /* x_proj split-K factor */
#define KSL_ (2048/SK_)   /* 64 */

typedef unsigned short u16;
typedef __attribute__((ext_vector_type(8))) short short8;
typedef __attribute__((ext_vector_type(8))) __bf16 bf16x8;
typedef __attribute__((ext_vector_type(4))) float f32x4;

__device__ __forceinline__ float softplusf_(float v) {
  return (v > 20.f) ? v : log1pf(expf(v));
}
__device__ __forceinline__ u16 f2bf(float f) {
  union { float f; unsigned u; } v; v.f = f;
  unsigned r = v.u + 0x7fffu + ((v.u >> 16) & 1u);
  return (u16)(r >> 16);
}
__device__ __forceinline__ float bf2f(u16 h) {
  union { unsigned u; float f; } v; v.u = ((unsigned)h) << 16;
  return v.f;
}
__device__ __forceinline__ void gload16(const void* g, void* l) {
  __builtin_amdgcn_global_load_lds(
      (const __attribute__((address_space(1))) unsigned*)g,
      (__attribute__((address_space(3))) unsigned*)l, 16, 0, 0);
}
__device__ __forceinline__ f32x4 mfma_bf16(short8 a, short8 b, f32x4 c) {
  return __builtin_amdgcn_mfma_f32_16x16x32_bf16(
      __builtin_bit_cast(bf16x8, a), __builtin_bit_cast(bf16x8, b), c, 0, 0, 0);
}

// ---------------- fp32 -> bf16 conversion ----------------
__global__ __launch_bounds__(256) void cvt_k(const float* __restrict__ in,
                                             u16* __restrict__ out) {
  int i = (blockIdx.x*256 + threadIdx.x) * 4;
  float4 v = *(const float4*)(in + i);
  ushort4 o;
  o.x = f2bf(v.x); o.y = f2bf(v.y); o.z = f2bf(v.z); o.w = f2bf(v.w);
  *(ushort4*)(out + i) = o;
}

// ---------------- bf16 MFMA GEMM ----------------
// C[m,n] = sum_k A[m,k]*Bt[n,k].  A: M x K bf16, Bt: N x K bf16, K%64==0,
// M%128==0, N%128==0. Block: 512 thr (8 waves), tile 128x128, BK=64.
// EPI: 0 plain f32 out; 1 fusion gate (bf16 out); 2 residual add (f32 out);
//      3 spectral filter (bf16 out); 4 plain bf16 out.
template<int EPI>
__global__ __launch_bounds__(512) void mgemm_k(
    const u16* __restrict__ Ab, const u16* __restrict__ Bb,
    void* __restrict__ Cout, int K, int ldc,
    const float* __restrict__ aux0, const u16* __restrict__ aux1,
    const float* __restrict__ aux2, const float* __restrict__ aux3)
{
  __shared__ __align__(16) u16 As[128*64];
  __shared__ __align__(16) u16 Bs[128*64];
  const int t = threadIdx.x;
  const int lane = t & 63;
  const int w = t >> 6;                 // 0..7
  const int wm = w >> 2, wn = w & 3;    // wave sub-tile: rows 64*wm, cols 32*wn
  const int M0 = blockIdx.y * 128, N0 = blockIdx.x * 128;

  f32x4 acc[4][2] = {};

  for (int k0 = 0; k0 < K; k0 += 64) {
    #pragma unroll
    for (int q = 0; q < 2; q++) {       // A tile: 1024 16B-units
      int u = q*512 + t;
      int row = u >> 3, gpr = u & 7;
      int grp = gpr ^ (row & 7);        // XOR swizzle
      gload16(Ab + (size_t)(M0+row)*K + k0 + grp*8, &As[u*8]);
    }
    #pragma unroll
    for (int q = 0; q < 2; q++) {       // B tile
      int u = q*512 + t;
      int row = u >> 3, gpr = u & 7;
      int grp = gpr ^ (row & 7);
      gload16(Bb + (size_t)(N0+row)*K + k0 + grp*8, &Bs[u*8]);
    }
    __syncthreads();
    #pragma unroll
    for (int kk = 0; kk < 2; kk++) {
      const int quad = lane >> 4;
      const int grp = kk*4 + quad;
      short8 af[4], bf[2];
      #pragma unroll
      for (int i = 0; i < 4; i++) {
        int row = wm*64 + i*16 + (lane & 15);
        af[i] = *(const short8*)&As[(row*8 + (grp ^ (row & 7)))*8];
      }
      #pragma unroll
      for (int j = 0; j < 2; j++) {
        int row = wn*32 + j*16 + (lane & 15);
        bf[j] = *(const short8*)&Bs[(row*8 + (grp ^ (row & 7)))*8];
      }
      #pragma unroll
      for (int i = 0; i < 4; i++)
        #pragma unroll
        for (int j = 0; j < 2; j++)
          acc[i][j] = mfma_bf16(af[i], bf[j], acc[i][j]);
    }
    __syncthreads();
  }

  // C/D layout: col = lane&15, row = (lane>>4)*4 + r
  #pragma unroll
  for (int i = 0; i < 4; i++) {
    int mbase = M0 + wm*64 + i*16 + (lane >> 4)*4;
    #pragma unroll
    for (int j = 0; j < 2; j++) {
      int n = N0 + wn*32 + j*16 + (lane & 15);
      #pragma unroll
      for (int r = 0; r < 4; r++) {
        int m = mbase + r;
        float v = acc[i][j][r];
        if (EPI == 0) {
          ((float*)Cout)[(size_t)m*ldc + n] = v;
        } else if (EPI == 1) {          // fusion gate
          float g  = 1.f/(1.f+expf(-(v + aux0[n])));
          float ys = bf2f(aux1[(size_t)m*4096 + n]);
          float yp = bf2f(aux1[(size_t)m*4096 + 2048 + n]);
          float z  = aux2[(size_t)m*4096 + 2048 + n];
          float zs = z/(1.f+expf(-z));
          ((u16*)Cout)[(size_t)m*ldc + n] = f2bf((g*ys + (1.f-g)*yp)*zs);
        } else if (EPI == 2) {          // residual add
          ((float*)Cout)[(size_t)m*ldc + n] = v + aux2[(size_t)m*ldc + n];
        } else if (EPI == 3) {          // spectral filter, complex pair via shfl
          float pv = __shfl_xor(v, 1, 64);
          int f = n >> 1;
          float outv = 0.f;
          if (f < NFFT_) {
            int c = m & (INNER_-1);
            float d  = expf(-aux2[c] * (float)f * (1.f/512.f));
            float wr = aux0[c*NFFT_+f]*d, wi = aux3[c*NFFT_+f]*d;
            float a = (n & 1) ? pv : v;
            float b = (n & 1) ? v : pv;
            outv = (n & 1) ? (a*wi + b*wr) : (a*wr - b*wi);
          }
          ((u16*)Cout)[(size_t)m*ldc + n] = f2bf(outv);
        } else {                        // 4: plain bf16
          ((u16*)Cout)[(size_t)m*ldc + n] = f2bf(v);
        }
      }
    }
  }
}

// ---------------- x_proj split-K: part[sk][m][40] = xconv[m, sk*64:+64] @ W^T ----
__global__ __launch_bounds__(256) void xproj_k(
    const float* __restrict__ xconv, const float* __restrict__ W,
    float* __restrict__ part)
{
  __shared__ float Bs[40][KSL_+4];
  const int sk = blockIdx.x, mt = blockIdx.y;
  const int k0 = sk*KSL_;
  for (int i = threadIdx.x; i < 40*KSL_; i += 256) {
    int n = i >> 6, k = i & (KSL_-1);
    Bs[n][k] = W[(size_t)n*2048 + k0 + k];
  }
  __syncthreads();
  const int m = mt*256 + threadIdx.x;
  const float* arow = xconv + (size_t)m*2048 + k0;
  float acc[40];
  #pragma unroll
  for (int j=0;j<40;j++) acc[j]=0.f;
  for (int k = 0; k < KSL_; k += 4) {
    float4 a = *(const float4*)(arow + k);
    #pragma unroll
    for (int j = 0; j < 40; j++) {
      float4 b = *(const float4*)&Bs[j][k];
      acc[j] += a.x*b.x + a.y*b.y + a.z*b.z + a.w*b.w;
    }
  }
  float* o = part + ((size_t)sk*M_ + m)*40;
  #pragma unroll
  for (int j = 0; j < 10; j++)
    *(float4*)(o + j*4) = make_float4(acc[j*4], acc[j*4+1], acc[j*4+2], acc[j*4+3]);
}

__global__ __launch_bounds__(256) void xpred_k(const float* __restrict__ part,
                                               float* __restrict__ xdbc)
{
  int i = blockIdx.x*256 + threadIdx.x;   // 81920 total
  float s = 0.f;
  #pragma unroll
  for (int sk = 0; sk < SK_; sk++) s += part[(size_t)sk*81920 + i];
  xdbc[i] = s;
}

// ---------------- depthwise causal conv(4) + silu ----------------
__global__ __launch_bounds__(256) void conv_silu_k(
    const float* __restrict__ xz, const float* __restrict__ cw,
    const float* __restrict__ cb, float* __restrict__ xc)
{
  int idx = blockIdx.x*256 + threadIdx.x;
  int c = idx & (INNER_-1);
  int m = idx >> 11;
  int l = m & (L_-1);
  const float* base = xz + (size_t)m*4096 + c;
  float w0=cw[c*4+0], w1=cw[c*4+1], w2=cw[c*4+2], w3=cw[c*4+3];
  float s = cb[c] + w3*base[0];
  if (l >= 1) s += w2*base[-4096];
  if (l >= 2) s += w1*base[-2*4096];
  if (l >= 3) s += w0*base[-3*4096];
  xc[(size_t)m*INNER_ + c] = s/(1.f+expf(-s));
}

// ---------------- SSM chunked scan ----------------
__global__ __launch_bounds__(256) void scan1_k(
    const float* __restrict__ xdbc, const float* __restrict__ xconv,
    const float* __restrict__ A_log, const float* __restrict__ dtw,
    const float* __restrict__ dtb, float* __restrict__ Pq)
{
  int idx = blockIdx.x*256 + threadIdx.x;
  int e  = idx & (INNER_-1);
  int bc = idx >> 11;
  int ch = bc & (NCH_-1);
  int b  = bc >> 4;
  float A[STATE_];
  #pragma unroll
  for (int s=0;s<STATE_;s++) A[s] = -expf(A_log[e*STATE_+s]);
  float w[DTR_];
  #pragma unroll
  for (int r=0;r<DTR_;r++) w[r] = dtw[e*DTR_+r];
  float bias = dtb[e];
  float h[STATE_] = {};
  float sdt = 0.f;
  int mbase = b*L_ + ch*CHL_;
  for (int l=0;l<CHL_;l++) {
    int m = mbase + l;
    const float* row = xdbc + (size_t)m*40;
    float v = bias;
    #pragma unroll
    for (int r=0;r<DTR_;r++) v += row[r]*w[r];
    float dt = softplusf_(v);
    sdt += dt;
    float dx = dt * xconv[(size_t)m*INNER_ + e];
    #pragma unroll
    for (int s=0;s<STATE_;s++) {
      float dA = expf(dt*A[s]);
      h[s] = dA*h[s] + dx*row[8+s];
    }
  }
  float* o = Pq + (size_t)idx*32;
  #pragma unroll
  for (int s=0;s<STATE_;s++) { o[s] = expf(A[s]*sdt); o[16+s] = h[s]; }
}

__global__ __launch_bounds__(256) void scan2_k(const float* __restrict__ Pq,
                                               float* __restrict__ hin)
{
  int idx = blockIdx.x*256 + threadIdx.x;
  int e = idx & (INNER_-1);
  int b = idx >> 11;
  float h[STATE_] = {};
  for (int ch=0; ch<NCH_; ch++) {
    size_t tix = ((size_t)(b*NCH_+ch)*INNER_ + e);
    float* o = hin + tix*16;
    const float* pq = Pq + tix*32;
    #pragma unroll
    for (int s=0;s<STATE_;s++) o[s] = h[s];
    #pragma unroll
    for (int s=0;s<STATE_;s++) h[s] = pq[s]*h[s] + pq[16+s];
  }
}

__global__ __launch_bounds__(256) void scan3_k(
    const float* __restrict__ xdbc, const float* __restrict__ xconv,
    const float* __restrict__ A_log, const float* __restrict__ dtw,
    const float* __restrict__ dtb, const float* __restrict__ Dp,
    const float* __restrict__ hin, u16* __restrict__ ycat)
{
  int idx = blockIdx.x*256 + threadIdx.x;
  int e  = idx & (INNER_-1);
  int bc = idx >> 11;
  int ch = bc & (NCH_-1);
  int b  = bc >> 4;
  float A[STATE_];
  #pragma unroll
  for (int s=0;s<STATE_;s++) A[s] = -expf(A_log[e*STATE_+s]);
  float w[DTR_];
  #pragma unroll
  for (int r=0;r<DTR_;r++) w[r] = dtw[e*DTR_+r];
  float bias = dtb[e];
  float Dv = Dp[e];
  float h[STATE_];
  const float* hi = hin + (size_t)idx*16;
  #pragma unroll
  for (int s=0;s<STATE_;s++) h[s] = hi[s];
  int mbase = b*L_ + ch*CHL_;
  for (int l=0;l<CHL_;l++) {
    int m = mbase + l;
    const float* row = xdbc + (size_t)m*40;
    float v = bias;
    #pragma unroll
    for (int r=0;r<DTR_;r++) v += row[r]*w[r];
    float dt = softplusf_(v);
    float xcv = xconv[(size_t)m*INNER_ + e];
    float dx = dt * xcv;
    float y = 0.f;
    #pragma unroll
    for (int s=0;s<STATE_;s++) {
      float dA = expf(dt*A[s]);
      h[s] = dA*h[s] + dx*row[8+s];
      y += h[s]*row[24+s];
    }
    ycat[(size_t)m*4096 + e] = f2bf(y + xcv*Dv);
  }
}

// ---------------- transposes ----------------
__global__ __launch_bounds__(256) void transpose_fwd_k(const float* __restrict__ xz,
                                                       u16* __restrict__ xt)
{
  __shared__ float tile[32][33];
  int tx = threadIdx.x & 31, ty = threadIdx.x >> 5;
  int l0 = blockIdx.x*32, c0 = blockIdx.y*32, b = blockIdx.z;
  #pragma unroll
  for (int j=0;j<4;j++) {
    int l = l0 + ty + j*8;
    tile[ty+j*8][tx] = xz[(size_t)(b*L_+l)*4096 + (c0+tx)];
  }
  __syncthreads();
  #pragma unroll
  for (int j=0;j<4;j++) {
    int c = c0 + ty + j*8;
    xt[(size_t)(b*INNER_+c)*L_ + (l0+tx)] = f2bf(tile[tx][ty+j*8]);
  }
}

__global__ __launch_bounds__(256) void transpose_bwd_k(const u16* __restrict__ yt,
                                                       u16* __restrict__ ycat)
{
  __shared__ float tile[32][33];
  int tx = threadIdx.x & 31, ty = threadIdx.x >> 5;
  int l0 = blockIdx.x*32, c0 = blockIdx.y*32, b = blockIdx.z;
  #pragma unroll
  for (int j=0;j<4;j++) {
    int c = c0 + ty + j*8;
    tile[ty+j*8][tx] = bf2f(yt[(size_t)(b*INNER_+c)*L_ + (l0+tx)]);
  }
  __syncthreads();
  #pragma unroll
  for (int j=0;j<4;j++) {
    int l = l0 + ty + j*8;
    ycat[(size_t)(b*L_+l)*4096 + 2048 + (c0+tx)] = f2bf(tile[tx][ty+j*8]);
  }
}

// ---------------- DFT matrix generation (bf16, K-contiguous) ----------------
__global__ __launch_bounds__(256) void genWdftb_k(u16* __restrict__ W) {
  int idx = blockIdx.x*256 + threadIdx.x;  // col*1024 + l ; col < NFP_
  int l = idx & (L_-1);
  int col = idx >> 10;
  float v = 0.f;
  int f = col >> 1;
  if (f < NFFT_) {
    int ph = (l*f) & (L_-1);
    float th = (float)ph * (6.283185307179586f / (float)L_);
    v = (col & 1) ? -sinf(th) : cosf(th);
  }
  W[idx] = f2bf(v);
}

__global__ __launch_bounds__(256) void genWinvb_k(u16* __restrict__ W) {
  int idx = blockIdx.x*256 + threadIdx.x;  // l*NFP_ + r
  int r = idx % NFP_;
  int l = idx / NFP_;
  int f = r >> 1;
  float v = 0.f;
  if (f < NFFT_) {
    bool edge = (f == 0) || (f == 512);
    float sc = (edge ? 1.f : 2.f) / (float)L_;
    int ph = (f*l) & (L_-1);
    float th = (float)ph * (6.283185307179586f / (float)L_);
    if (r & 1) v = edge ? 0.f : -sc*sinf(th);
    else       v = sc*cosf(th);
  }
  W[idx] = f2bf(v);
}

// ---------------- layernorm ----------------
__global__ __launch_bounds__(256) void ln_k(const float* __restrict__ inp,
    const float* __restrict__ gma, const float* __restrict__ bta,
    float* __restrict__ out)
{
  int m = blockIdx.x;
  const float* row = inp + (size_t)m*DM_;
  float s=0.f, s2=0.f;
  float v[4];
  #pragma unroll
  for (int j=0;j<4;j++) {
    v[j] = row[threadIdx.x + j*256];
    s += v[j]; s2 += v[j]*v[j];
  }
  #pragma unroll
  for (int off=32; off>=1; off>>=1) {
    s  += __shfl_down(s, off);
    s2 += __shfl_down(s2, off);
  }
  __shared__ float rs[4], rs2[4], stats[2];
  int wid = threadIdx.x >> 6;
  if ((threadIdx.x & 63) == 0) { rs[wid]=s; rs2[wid]=s2; }
  __syncthreads();
  if (threadIdx.x == 0) {
    float ts  = rs[0]+rs[1]+rs[2]+rs[3];
    float ts2 = rs2[0]+rs2[1]+rs2[2]+rs2[3];
    float mu  = ts/(float)DM_;
    float var = ts2/(float)DM_ - mu*mu;
    stats[0] = mu; stats[1] = rsqrtf(var + 1e-5f);
  }
  __syncthreads();
  float mu = stats[0], rstd = stats[1];
  #pragma unroll
  for (int j=0;j<4;j++) {
    int n = threadIdx.x + j*256;
    out[(size_t)m*DM_ + n] = (v[j]-mu)*rstd*gma[n] + bta[n];
  }
}

extern "C" void kernel_launch(void* const* d_in, const int* in_sizes, int n_in,
                              void* d_out, int out_size, void* d_ws, size_t ws_size,
                              hipStream_t stream)
{
  const float* x       = (const float*)d_in[0];
  const float* in_w    = (const float*)d_in[1];
  const float* conv_w  = (const float*)d_in[2];
  const float* conv_b  = (const float*)d_in[3];
  const float* A_log   = (const float*)d_in[4];
  const float* Dp      = (const float*)d_in[5];
  const float* xproj_w = (const float*)d_in[6];
  const float* dt_w    = (const float*)d_in[7];
  const float* dt_b    = (const float*)d_in[8];
  const float* f_re    = (const float*)d_in[9];
  const float* f_im    = (const float*)d_in[10];
  const float* s_dec   = (const float*)d_in[11];
  const float* fus_w   = (const float*)d_in[12];
  const float* fus_b   = (const float*)d_in[13];
  const float* out_w   = (const float*)d_in[14];
  const float* ln_g    = (const float*)d_in[15];
  const float* ln_b    = (const float*)d_in[16];
  float* out = (float*)d_out;

  // ---- workspace carve (fp32 region then bf16 region), ~134 MB total ----
  float* ws    = (float*)d_ws;
  float* xz    = ws;                       // 8388608  (M x 4096)
  float* xconv = xz    + 8388608;          // 4194304  (M x 2048), reused as outp
  float* xdbc  = xconv + 4194304;          // 81920    (M x 40)
  float* Pq    = xdbc  + 81920;            // 2097152
  float* hin   = Pq    + 2097152;          // 1048576
  u16* ub      = (u16*)(hin + 1048576);
  u16* xb      = ub;                       // 2097152   x bf16
  u16* inwb    = xb    + 2097152;          // 4194304   in_w bf16; reused as yt
  u16* fuswb   = inwb  + 4194304;          // 8388608   fus_w bf16
  u16* outwb   = fuswb + 8388608;          // 2097152   out_w bf16
  u16* xt      = outwb + 2097152;          // 4194304   x_inner^T bf16; reused as ycomb
  u16* Wb      = xt    + 4194304;          // 1179648   Wdft then Winv
  u16* XFb     = Wb    + 1179648;          // 4718592   (MD x NFP) bf16
  u16* ycat    = XFb   + 4718592;          // 8388608   (M x 4096) bf16
  u16* yt      = inwb;
  u16* ycomb   = xt;
  float* outp  = xconv;
  float* part  = (float*)ycat;             // 2.6M floats, dead before scan3 writes ycat

  // 0. convert GEMM operands to bf16
  cvt_k<<<2097152/1024, 256, 0, stream>>>(x, xb);
  cvt_k<<<4194304/1024, 256, 0, stream>>>(in_w, inwb);
  cvt_k<<<8388608/1024, 256, 0, stream>>>(fus_w, fuswb);
  cvt_k<<<2097152/1024, 256, 0, stream>>>(out_w, outwb);

  // 1. xz = x @ in_proj_w^T   (2048 x 4096 x 1024) MFMA
  mgemm_k<0><<<dim3(4096/128, M_/128), 512, 0, stream>>>(
      xb, inwb, xz, 1024, 4096, nullptr, nullptr, nullptr, nullptr);
  // 2. depthwise conv + silu
  conv_silu_k<<<(M_*INNER_)/256, 256, 0, stream>>>(xz, conv_w, conv_b, xconv);
  // 3. x_dbc = x_conv @ x_proj_w^T  (2048 x 40 x 2048) split-K fp32
  xproj_k<<<dim3(SK_, M_/256), 256, 0, stream>>>(xconv, xproj_w, part);
  xpred_k<<<(M_*40)/256, 256, 0, stream>>>(part, xdbc);
  // 4-6. chunked SSM scan -> y_cat[:, :2048] (bf16)
  scan1_k<<<(B_*NCH_*INNER_)/256, 256, 0, stream>>>(xdbc, xconv, A_log, dt_w, dt_b, Pq);
  scan2_k<<<MD_/256, 256, 0, stream>>>(Pq, hin);
  scan3_k<<<(B_*NCH_*INNER_)/256, 256, 0, stream>>>(xdbc, xconv, A_log, dt_w, dt_b, Dp, hin, ycat);
  // 7. transpose x_inner -> (b,c,l) bf16
  transpose_fwd_k<<<dim3(L_/32, INNER_/32, B_), 256, 0, stream>>>(xz, xt);
  // 8. forward DFT + fused spectral filter: XFb = filt(xt @ Wdft)
  genWdftb_k<<<(NFP_*1024)/256, 256, 0, stream>>>(Wb);
  mgemm_k<3><<<dim3(NFP_/128, MD_/128), 512, 0, stream>>>(
      xt, Wb, XFb, 1024, NFP_, f_re, nullptr, s_dec, f_im);
  // 9. inverse DFT: yt = XFb @ Winv  (4096 x 1024 x 1152) -> bf16
  genWinvb_k<<<(NFP_*1024)/256, 256, 0, stream>>>(Wb);
  mgemm_k<4><<<dim3(1024/128, MD_/128), 512, 0, stream>>>(
      XFb, Wb, yt, NFP_, 1024, nullptr, nullptr, nullptr, nullptr);
  // 10. transpose back -> y_cat[:, 2048:]
  transpose_bwd_k<<<dim3(L_/32, INNER_/32, B_), 256, 0, stream>>>(yt, ycat);
  // 11. fusion GEMM + gate epilogue (2048 x 2048 x 4096) -> ycomb bf16
  mgemm_k<1><<<dim3(2048/128, M_/128), 512, 0, stream>>>(
      ycat, fuswb, ycomb, 4096, 2048, fus_b, ycat, xz, nullptr);
  // 12. out proj + residual (2048 x 1024 x 2048) -> fp32
  mgemm_k<2><<<dim3(1024/128, M_/128), 512, 0, stream>>>(
      ycomb, outwb, outp, 2048, 1024, nullptr, nullptr, x, nullptr);
  // 13. layernorm -> d_out
  ln_k<<<M_, 256, 0, stream>>>(outp, ln_g, ln_b, out);
}

// Round 4
// 476.698 us; speedup vs baseline: 3.5501x; 1.3025x over previous
//
#include <hip/hip_runtime.h>
#include <math.h>

#define B_ 2
#define L_ 1024
#define DM_ 1024
#define STATE_ 16
#define CONV_ 4
#define DTR_ 8
#define INNER_ 2048
#define M_ (B_*L_)        /* 2048 rows (b,l) */
#define MD_ (B_*INNER_)   /* 4096 rows (b,c) */
#define NFFT_ 513
#define NFP_ 1152         /* 2*513=1026 padded to multiple of 128 */
#define NCH_ 32
#define CHL_ 32
#define SK_ 32            /* x_proj split-K factor */
#define KSL_ (2048/SK_)   /* 64 */

typedef unsigned short u16;
typedef __attribute__((ext_vector_type(8))) short short8;
typedef __attribute__((ext_vector_type(8))) __bf16 bf16x8;
typedef __attribute__((ext_vector_type(4))) float f32x4;

__device__ __forceinline__ float frcp_(float x) { return __builtin_amdgcn_rcpf(x); }
__device__ __forceinline__ float fexp_(float x) { return __expf(x); }
__device__ __forceinline__ float fsigm_(float x) { return frcp_(1.f + __expf(-x)); }
__device__ __forceinline__ float fsilu_(float x) { return x * frcp_(1.f + __expf(-x)); }
__device__ __forceinline__ float fsoftplus_(float v) {
  return (v > 20.f) ? v : __logf(1.f + __expf(v));
}
__device__ __forceinline__ u16 f2bf(float f) {
  union { float f; unsigned u; } v; v.f = f;
  unsigned r = v.u + 0x7fffu + ((v.u >> 16) & 1u);
  return (u16)(r >> 16);
}
__device__ __forceinline__ float bf2f(u16 h) {
  union { unsigned u; float f; } v; v.u = ((unsigned)h) << 16;
  return v.f;
}
__device__ __forceinline__ void gload16(const void* g, void* l) {
  __builtin_amdgcn_global_load_lds(
      (const __attribute__((address_space(1))) unsigned*)g,
      (__attribute__((address_space(3))) unsigned*)l, 16, 0, 0);
}
__device__ __forceinline__ f32x4 mfma_bf16(short8 a, short8 b, f32x4 c) {
  return __builtin_amdgcn_mfma_f32_16x16x32_bf16(
      __builtin_bit_cast(bf16x8, a), __builtin_bit_cast(bf16x8, b), c, 0, 0, 0);
}

// ---------------- fp32 -> bf16 conversion ----------------
__global__ __launch_bounds__(256) void cvt_k(const float* __restrict__ in,
                                             u16* __restrict__ out) {
  int i = (blockIdx.x*256 + threadIdx.x) * 4;
  float4 v = *(const float4*)(in + i);
  ushort4 o;
  o.x = f2bf(v.x); o.y = f2bf(v.y); o.z = f2bf(v.z); o.w = f2bf(v.w);
  *(ushort4*)(out + i) = o;
}

// ---------------- bf16 MFMA GEMM ----------------
// C[m,n] = sum_k A[m,k]*Bt[n,k].  A: M x K bf16, Bt: N x K bf16, K%64==0,
// M%128==0, N%128==0. Block: 512 thr (8 waves), tile 128x128, BK=64.
// EPI: 0 plain f32 out; 1 fusion gate (bf16 out); 2 residual add (f32 out);
//      3 spectral filter (bf16 out); 4 plain bf16 out.
template<int EPI>
__global__ __launch_bounds__(512) void mgemm_k(
    const u16* __restrict__ Ab, const u16* __restrict__ Bb,
    void* __restrict__ Cout, int K, int ldc,
    const float* __restrict__ aux0, const u16* __restrict__ aux1,
    const float* __restrict__ aux2, const float* __restrict__ aux3)
{
  __shared__ __align__(16) u16 As[128*64];
  __shared__ __align__(16) u16 Bs[128*64];
  const int t = threadIdx.x;
  const int lane = t & 63;
  const int w = t >> 6;                 // 0..7
  const int wm = w >> 2, wn = w & 3;    // wave sub-tile: rows 64*wm, cols 32*wn
  const int M0 = blockIdx.y * 128, N0 = blockIdx.x * 128;

  f32x4 acc[4][2] = {};

  for (int k0 = 0; k0 < K; k0 += 64) {
    #pragma unroll
    for (int q = 0; q < 2; q++) {       // A tile: 1024 16B-units
      int u = q*512 + t;
      int row = u >> 3, gpr = u & 7;
      int grp = gpr ^ (row & 7);        // XOR swizzle
      gload16(Ab + (size_t)(M0+row)*K + k0 + grp*8, &As[u*8]);
    }
    #pragma unroll
    for (int q = 0; q < 2; q++) {       // B tile
      int u = q*512 + t;
      int row = u >> 3, gpr = u & 7;
      int grp = gpr ^ (row & 7);
      gload16(Bb + (size_t)(N0+row)*K + k0 + grp*8, &Bs[u*8]);
    }
    __syncthreads();
    #pragma unroll
    for (int kk = 0; kk < 2; kk++) {
      const int quad = lane >> 4;
      const int grp = kk*4 + quad;
      short8 af[4], bf[2];
      #pragma unroll
      for (int i = 0; i < 4; i++) {
        int row = wm*64 + i*16 + (lane & 15);
        af[i] = *(const short8*)&As[(row*8 + (grp ^ (row & 7)))*8];
      }
      #pragma unroll
      for (int j = 0; j < 2; j++) {
        int row = wn*32 + j*16 + (lane & 15);
        bf[j] = *(const short8*)&Bs[(row*8 + (grp ^ (row & 7)))*8];
      }
      #pragma unroll
      for (int i = 0; i < 4; i++)
        #pragma unroll
        for (int j = 0; j < 2; j++)
          acc[i][j] = mfma_bf16(af[i], bf[j], acc[i][j]);
    }
    __syncthreads();
  }

  // C/D layout: col = lane&15, row = (lane>>4)*4 + r
  #pragma unroll
  for (int i = 0; i < 4; i++) {
    int mbase = M0 + wm*64 + i*16 + (lane >> 4)*4;
    #pragma unroll
    for (int j = 0; j < 2; j++) {
      int n = N0 + wn*32 + j*16 + (lane & 15);
      #pragma unroll
      for (int r = 0; r < 4; r++) {
        int m = mbase + r;
        float v = acc[i][j][r];
        if (EPI == 0) {
          ((float*)Cout)[(size_t)m*ldc + n] = v;
        } else if (EPI == 1) {          // fusion gate
          float g  = fsigm_(v + aux0[n]);
          float ys = bf2f(aux1[(size_t)m*4096 + n]);
          float yp = bf2f(aux1[(size_t)m*4096 + 2048 + n]);
          float z  = aux2[(size_t)m*4096 + 2048 + n];
          ((u16*)Cout)[(size_t)m*ldc + n] = f2bf((g*ys + (1.f-g)*yp)*fsilu_(z));
        } else if (EPI == 2) {          // residual add
          ((float*)Cout)[(size_t)m*ldc + n] = v + aux2[(size_t)m*ldc + n];
        } else if (EPI == 3) {          // spectral filter, complex pair via shfl
          float pv = __shfl_xor(v, 1, 64);
          int f = n >> 1;
          float outv = 0.f;
          if (f < NFFT_) {
            int c = m & (INNER_-1);
            float d  = fexp_(-aux2[c] * (float)f * (1.f/512.f));
            float wr = aux0[c*NFFT_+f]*d, wi = aux3[c*NFFT_+f]*d;
            float a = (n & 1) ? pv : v;
            float b = (n & 1) ? v : pv;
            outv = (n & 1) ? (a*wi + b*wr) : (a*wr - b*wi);
          }
          ((u16*)Cout)[(size_t)m*ldc + n] = f2bf(outv);
        } else {                        // 4: plain bf16
          ((u16*)Cout)[(size_t)m*ldc + n] = f2bf(v);
        }
      }
    }
  }
}

// ---------------- x_proj split-K: part[sk][m][40] = xconv[m, sk*64:+64] @ W^T ----
__global__ __launch_bounds__(256) void xproj_k(
    const float* __restrict__ xconv, const float* __restrict__ W,
    float* __restrict__ part)
{
  __shared__ float Bs[40][KSL_+4];
  const int sk = blockIdx.x, mt = blockIdx.y;
  const int k0 = sk*KSL_;
  for (int i = threadIdx.x; i < 40*KSL_; i += 256) {
    int n = i >> 6, k = i & (KSL_-1);
    Bs[n][k] = W[(size_t)n*2048 + k0 + k];
  }
  __syncthreads();
  const int m = mt*256 + threadIdx.x;
  const float* arow = xconv + (size_t)m*2048 + k0;
  float acc[40];
  #pragma unroll
  for (int j=0;j<40;j++) acc[j]=0.f;
  for (int k = 0; k < KSL_; k += 4) {
    float4 a = *(const float4*)(arow + k);
    #pragma unroll
    for (int j = 0; j < 40; j++) {
      float4 b = *(const float4*)&Bs[j][k];
      acc[j] += a.x*b.x + a.y*b.y + a.z*b.z + a.w*b.w;
    }
  }
  float* o = part + ((size_t)sk*M_ + m)*40;
  #pragma unroll
  for (int j = 0; j < 10; j++)
    *(float4*)(o + j*4) = make_float4(acc[j*4], acc[j*4+1], acc[j*4+2], acc[j*4+3]);
}

__global__ __launch_bounds__(256) void xpred_k(const float* __restrict__ part,
                                               float* __restrict__ xdbc)
{
  int i = blockIdx.x*256 + threadIdx.x;   // 81920 total
  float s = 0.f;
  #pragma unroll
  for (int sk = 0; sk < SK_; sk++) s += part[(size_t)sk*81920 + i];
  xdbc[i] = s;
}

// ---------------- depthwise causal conv(4) + silu ----------------
__global__ __launch_bounds__(256) void conv_silu_k(
    const float* __restrict__ xz, const float* __restrict__ cw,
    const float* __restrict__ cb, float* __restrict__ xc)
{
  int idx = blockIdx.x*256 + threadIdx.x;
  int c = idx & (INNER_-1);
  int m = idx >> 11;
  int l = m & (L_-1);
  const float* base = xz + (size_t)m*4096 + c;
  float w0=cw[c*4+0], w1=cw[c*4+1], w2=cw[c*4+2], w3=cw[c*4+3];
  float s = cb[c] + w3*base[0];
  if (l >= 1) s += w2*base[-4096];
  if (l >= 2) s += w1*base[-2*4096];
  if (l >= 3) s += w0*base[-3*4096];
  xc[(size_t)m*INNER_ + c] = fsilu_(s);
}

// ---------------- SSM chunked scan ----------------
// Pq layout per (b,ch,e): [0..15] = P (chunk transfer), [16..31] = q, then
// scan2 overwrites q-slot with h_in for that chunk.
__global__ __launch_bounds__(256) void scan1_k(
    const float* __restrict__ xdbc, const float* __restrict__ xconv,
    const float* __restrict__ A_log, const float* __restrict__ dtw,
    const float* __restrict__ dtb, float* __restrict__ Pq)
{
  int idx = blockIdx.x*256 + threadIdx.x;   // (b*NCH+ch)*INNER + e
  int e  = idx & (INNER_-1);
  int bc = idx >> 11;
  int ch = bc & (NCH_-1);
  int b  = bc >> 5;
  float A[STATE_];
  #pragma unroll
  for (int s=0;s<STATE_;s++) A[s] = -fexp_(A_log[e*STATE_+s]);
  float w[DTR_];
  #pragma unroll
  for (int r=0;r<DTR_;r++) w[r] = dtw[e*DTR_+r];
  float bias = dtb[e];
  float h[STATE_] = {};
  float sdt = 0.f;
  int mbase = b*L_ + ch*CHL_;
  for (int l=0;l<CHL_;l++) {
    int m = mbase + l;
    const float* row = xdbc + (size_t)m*40;
    float v = bias;
    #pragma unroll
    for (int r=0;r<DTR_;r++) v += row[r]*w[r];
    float dt = fsoftplus_(v);
    sdt += dt;
    float dx = dt * xconv[(size_t)m*INNER_ + e];
    #pragma unroll
    for (int s=0;s<STATE_;s++) {
      float dA = fexp_(dt*A[s]);
      h[s] = dA*h[s] + dx*row[8+s];
    }
  }
  float* o = Pq + (size_t)idx*32;
  #pragma unroll
  for (int s=0;s<STATE_;s++) { o[s] = fexp_(A[s]*sdt); o[16+s] = h[s]; }
}

// combine chunks, parallel over (b,e,s); h_in written into the q slot
__global__ __launch_bounds__(256) void scan2_k(float* __restrict__ Pq)
{
  int idx = blockIdx.x*256 + threadIdx.x;   // b*(INNER*16) + e*16 + s ; 65536
  int s = idx & 15;
  int e = (idx >> 4) & (INNER_-1);
  int b = idx >> 15;
  float h = 0.f;
  for (int ch = 0; ch < NCH_; ch++) {
    size_t base = ((size_t)(b*NCH_+ch)*INNER_ + e)*32;
    float p = Pq[base + s];
    float q = Pq[base + 16 + s];
    Pq[base + 16 + s] = h;
    h = p*h + q;
  }
}

__global__ __launch_bounds__(256) void scan3_k(
    const float* __restrict__ xdbc, const float* __restrict__ xconv,
    const float* __restrict__ A_log, const float* __restrict__ dtw,
    const float* __restrict__ dtb, const float* __restrict__ Dp,
    const float* __restrict__ Pq, u16* __restrict__ ycat)
{
  int idx = blockIdx.x*256 + threadIdx.x;
  int e  = idx & (INNER_-1);
  int bc = idx >> 11;
  int ch = bc & (NCH_-1);
  int b  = bc >> 5;
  float A[STATE_];
  #pragma unroll
  for (int s=0;s<STATE_;s++) A[s] = -fexp_(A_log[e*STATE_+s]);
  float w[DTR_];
  #pragma unroll
  for (int r=0;r<DTR_;r++) w[r] = dtw[e*DTR_+r];
  float bias = dtb[e];
  float Dv = Dp[e];
  float h[STATE_];
  const float* hi = Pq + (size_t)idx*32 + 16;
  #pragma unroll
  for (int s=0;s<STATE_;s++) h[s] = hi[s];
  int mbase = b*L_ + ch*CHL_;
  for (int l=0;l<CHL_;l++) {
    int m = mbase + l;
    const float* row = xdbc + (size_t)m*40;
    float v = bias;
    #pragma unroll
    for (int r=0;r<DTR_;r++) v += row[r]*w[r];
    float dt = fsoftplus_(v);
    float xcv = xconv[(size_t)m*INNER_ + e];
    float dx = dt * xcv;
    float y = 0.f;
    #pragma unroll
    for (int s=0;s<STATE_;s++) {
      float dA = fexp_(dt*A[s]);
      h[s] = dA*h[s] + dx*row[8+s];
      y += h[s]*row[24+s];
    }
    ycat[(size_t)m*4096 + e] = f2bf(y + xcv*Dv);
  }
}

// ---------------- transposes ----------------
__global__ __launch_bounds__(256) void transpose_fwd_k(const float* __restrict__ xz,
                                                       u16* __restrict__ xt)
{
  __shared__ float tile[32][33];
  int tx = threadIdx.x & 31, ty = threadIdx.x >> 5;
  int l0 = blockIdx.x*32, c0 = blockIdx.y*32, b = blockIdx.z;
  #pragma unroll
  for (int j=0;j<4;j++) {
    int l = l0 + ty + j*8;
    tile[ty+j*8][tx] = xz[(size_t)(b*L_+l)*4096 + (c0+tx)];
  }
  __syncthreads();
  #pragma unroll
  for (int j=0;j<4;j++) {
    int c = c0 + ty + j*8;
    xt[(size_t)(b*INNER_+c)*L_ + (l0+tx)] = f2bf(tile[tx][ty+j*8]);
  }
}

__global__ __launch_bounds__(256) void transpose_bwd_k(const u16* __restrict__ yt,
                                                       u16* __restrict__ ycat)
{
  __shared__ float tile[32][33];
  int tx = threadIdx.x & 31, ty = threadIdx.x >> 5;
  int l0 = blockIdx.x*32, c0 = blockIdx.y*32, b = blockIdx.z;
  #pragma unroll
  for (int j=0;j<4;j++) {
    int c = c0 + ty + j*8;
    tile[ty+j*8][tx] = bf2f(yt[(size_t)(b*INNER_+c)*L_ + (l0+tx)]);
  }
  __syncthreads();
  #pragma unroll
  for (int j=0;j<4;j++) {
    int l = l0 + ty + j*8;
    ycat[(size_t)(b*L_+l)*4096 + 2048 + (c0+tx)] = f2bf(tile[tx][ty+j*8]);
  }
}

// ---------------- DFT matrix generation (bf16, K-contiguous) ----------------
__global__ __launch_bounds__(256) void genWdftb_k(u16* __restrict__ W) {
  int idx = blockIdx.x*256 + threadIdx.x;  // col*1024 + l ; col < NFP_
  int l = idx & (L_-1);
  int col = idx >> 10;
  float v = 0.f;
  int f = col >> 1;
  if (f < NFFT_) {
    int ph = (l*f) & (L_-1);
    float th = (float)ph * (6.283185307179586f / (float)L_);
    v = (col & 1) ? -__sinf(th) : __cosf(th);
  }
  W[idx] = f2bf(v);
}

__global__ __launch_bounds__(256) void genWinvb_k(u16* __restrict__ W) {
  int idx = blockIdx.x*256 + threadIdx.x;  // l*NFP_ + r
  int r = idx % NFP_;
  int l = idx / NFP_;
  int f = r >> 1;
  float v = 0.f;
  if (f < NFFT_) {
    bool edge = (f == 0) || (f == 512);
    float sc = (edge ? 1.f : 2.f) / (float)L_;
    int ph = (f*l) & (L_-1);
    float th = (float)ph * (6.283185307179586f / (float)L_);
    if (r & 1) v = edge ? 0.f : -sc*__sinf(th);
    else       v = sc*__cosf(th);
  }
  W[idx] = f2bf(v);
}

// ---------------- layernorm ----------------
__global__ __launch_bounds__(256) void ln_k(const float* __restrict__ inp,
    const float* __restrict__ gma, const float* __restrict__ bta,
    float* __restrict__ out)
{
  int m = blockIdx.x;
  const float* row = inp + (size_t)m*DM_;
  float s=0.f, s2=0.f;
  float v[4];
  #pragma unroll
  for (int j=0;j<4;j++) {
    v[j] = row[threadIdx.x + j*256];
    s += v[j]; s2 += v[j]*v[j];
  }
  #pragma unroll
  for (int off=32; off>=1; off>>=1) {
    s  += __shfl_down(s, off);
    s2 += __shfl_down(s2, off);
  }
  __shared__ float rs[4], rs2[4], stats[2];
  int wid = threadIdx.x >> 6;
  if ((threadIdx.x & 63) == 0) { rs[wid]=s; rs2[wid]=s2; }
  __syncthreads();
  if (threadIdx.x == 0) {
    float ts  = rs[0]+rs[1]+rs[2]+rs[3];
    float ts2 = rs2[0]+rs2[1]+rs2[2]+rs2[3];
    float mu  = ts/(float)DM_;
    float var = ts2/(float)DM_ - mu*mu;
    stats[0] = mu; stats[1] = rsqrtf(var + 1e-5f);
  }
  __syncthreads();
  float mu = stats[0], rstd = stats[1];
  #pragma unroll
  for (int j=0;j<4;j++) {
    int n = threadIdx.x + j*256;
    out[(size_t)m*DM_ + n] = (v[j]-mu)*rstd*gma[n] + bta[n];
  }
}

extern "C" void kernel_launch(void* const* d_in, const int* in_sizes, int n_in,
                              void* d_out, int out_size, void* d_ws, size_t ws_size,
                              hipStream_t stream)
{
  const float* x       = (const float*)d_in[0];
  const float* in_w    = (const float*)d_in[1];
  const float* conv_w  = (const float*)d_in[2];
  const float* conv_b  = (const float*)d_in[3];
  const float* A_log   = (const float*)d_in[4];
  const float* Dp      = (const float*)d_in[5];
  const float* xproj_w = (const float*)d_in[6];
  const float* dt_w    = (const float*)d_in[7];
  const float* dt_b    = (const float*)d_in[8];
  const float* f_re    = (const float*)d_in[9];
  const float* f_im    = (const float*)d_in[10];
  const float* s_dec   = (const float*)d_in[11];
  const float* fus_w   = (const float*)d_in[12];
  const float* fus_b   = (const float*)d_in[13];
  const float* out_w   = (const float*)d_in[14];
  const float* ln_g    = (const float*)d_in[15];
  const float* ln_b    = (const float*)d_in[16];
  float* out = (float*)d_out;

  // ---- workspace carve (fp32 region then bf16 region), ~138 MB total ----
  float* ws    = (float*)d_ws;
  float* xz    = ws;                       // 8388608  (M x 4096)
  float* xconv = xz    + 8388608;          // 4194304  (M x 2048), reused as outp
  float* xdbc  = xconv + 4194304;          // 81920    (M x 40)
  float* Pq    = xdbc  + 81920;            // 4194304  (B*NCH*INNER x 32), holds h_in too
  u16* ub      = (u16*)(Pq + 4194304);
  u16* xb      = ub;                       // 2097152   x bf16
  u16* inwb    = xb    + 2097152;          // 4194304   in_w bf16; reused as yt
  u16* fuswb   = inwb  + 4194304;          // 8388608   fus_w bf16
  u16* outwb   = fuswb + 8388608;          // 2097152   out_w bf16
  u16* xt      = outwb + 2097152;          // 4194304   x_inner^T bf16; reused as ycomb
  u16* Wb      = xt    + 4194304;          // 1179648   Wdft then Winv
  u16* XFb     = Wb    + 1179648;          // 4718592   (MD x NFP) bf16
  u16* ycat    = XFb   + 4718592;          // 8388608   (M x 4096) bf16
  u16* yt      = inwb;
  u16* ycomb   = xt;
  float* outp  = xconv;
  float* part  = (float*)ycat;             // 2.6M floats, dead before scan3 writes ycat

  // 0. convert GEMM operands to bf16
  cvt_k<<<2097152/1024, 256, 0, stream>>>(x, xb);
  cvt_k<<<4194304/1024, 256, 0, stream>>>(in_w, inwb);
  cvt_k<<<8388608/1024, 256, 0, stream>>>(fus_w, fuswb);
  cvt_k<<<2097152/1024, 256, 0, stream>>>(out_w, outwb);

  // 1. xz = x @ in_proj_w^T   (2048 x 4096 x 1024) MFMA
  mgemm_k<0><<<dim3(4096/128, M_/128), 512, 0, stream>>>(
      xb, inwb, xz, 1024, 4096, nullptr, nullptr, nullptr, nullptr);
  // 2. depthwise conv + silu
  conv_silu_k<<<(M_*INNER_)/256, 256, 0, stream>>>(xz, conv_w, conv_b, xconv);
  // 3. x_dbc = x_conv @ x_proj_w^T  (2048 x 40 x 2048) split-K fp32
  xproj_k<<<dim3(SK_, M_/256), 256, 0, stream>>>(xconv, xproj_w, part);
  xpred_k<<<(M_*40)/256, 256, 0, stream>>>(part, xdbc);
  // 4-6. chunked SSM scan -> y_cat[:, :2048] (bf16)
  scan1_k<<<(B_*NCH_*INNER_)/256, 256, 0, stream>>>(xdbc, xconv, A_log, dt_w, dt_b, Pq);
  scan2_k<<<(B_*INNER_*STATE_)/256, 256, 0, stream>>>(Pq);
  scan3_k<<<(B_*NCH_*INNER_)/256, 256, 0, stream>>>(xdbc, xconv, A_log, dt_w, dt_b, Dp, Pq, ycat);
  // 7. transpose x_inner -> (b,c,l) bf16
  transpose_fwd_k<<<dim3(L_/32, INNER_/32, B_), 256, 0, stream>>>(xz, xt);
  // 8. forward DFT + fused spectral filter: XFb = filt(xt @ Wdft)
  genWdftb_k<<<(NFP_*1024)/256, 256, 0, stream>>>(Wb);
  mgemm_k<3><<<dim3(NFP_/128, MD_/128), 512, 0, stream>>>(
      xt, Wb, XFb, 1024, NFP_, f_re, nullptr, s_dec, f_im);
  // 9. inverse DFT: yt = XFb @ Winv  (4096 x 1024 x 1152) -> bf16
  genWinvb_k<<<(NFP_*1024)/256, 256, 0, stream>>>(Wb);
  mgemm_k<4><<<dim3(1024/128, MD_/128), 512, 0, stream>>>(
      XFb, Wb, yt, NFP_, 1024, nullptr, nullptr, nullptr, nullptr);
  // 10. transpose back -> y_cat[:, 2048:]
  transpose_bwd_k<<<dim3(L_/32, INNER_/32, B_), 256, 0, stream>>>(yt, ycat);
  // 11. fusion GEMM + gate epilogue (2048 x 2048 x 4096) -> ycomb bf16
  mgemm_k<1><<<dim3(2048/128, M_/128), 512, 0, stream>>>(
      ycat, fuswb, ycomb, 4096, 2048, fus_b, ycat, xz, nullptr);
  // 12. out proj + residual (2048 x 1024 x 2048) -> fp32
  mgemm_k<2><<<dim3(1024/128, M_/128), 512, 0, stream>>>(
      ycomb, outwb, outp, 2048, 1024, nullptr, nullptr, x, nullptr);
  // 13. layernorm -> d_out
  ln_k<<<M_, 256, 0, stream>>>(outp, ln_g, ln_b, out);
}

// Round 5
// 464.783 us; speedup vs baseline: 3.6411x; 1.0256x over previous
//
#include <hip/hip_runtime.h>
#include <math.h>

#define B_ 2
#define L_ 1024
#define DM_ 1024
#define STATE_ 16
#define CONV_ 4
#define DTR_ 8
#define INNER_ 2048
#define M_ (B_*L_)        /* 2048 rows (b,l) */
#define MD_ (B_*INNER_)   /* 4096 rows (b,c) */
#define NFFT_ 513
#define NFP_ 1152         /* 2*513=1026 padded to multiple of 128 */
#define NCH_ 32
#define CHL_ 32
#define SK_ 32            /* x_proj split-K factor */
#define KSL_ (2048/SK_)   /* 64 */

typedef unsigned short u16;
typedef __attribute__((ext_vector_type(8))) short short8;
typedef __attribute__((ext_vector_type(8))) __bf16 bf16x8;
typedef __attribute__((ext_vector_type(4))) float f32x4;

__device__ __forceinline__ float frcp_(float x) { return __builtin_amdgcn_rcpf(x); }
__device__ __forceinline__ float fexp_(float x) { return __expf(x); }
__device__ __forceinline__ float fsigm_(float x) { return frcp_(1.f + __expf(-x)); }
__device__ __forceinline__ float fsilu_(float x) { return x * frcp_(1.f + __expf(-x)); }
__device__ __forceinline__ float fsoftplus_(float v) {
  return (v > 20.f) ? v : __logf(1.f + __expf(v));
}
__device__ __forceinline__ u16 f2bf(float f) {
  union { float f; unsigned u; } v; v.f = f;
  unsigned r = v.u + 0x7fffu + ((v.u >> 16) & 1u);
  return (u16)(r >> 16);
}
__device__ __forceinline__ float bf2f(u16 h) {
  union { unsigned u; float f; } v; v.u = ((unsigned)h) << 16;
  return v.f;
}
__device__ __forceinline__ void gload16(const void* g, void* l) {
  __builtin_amdgcn_global_load_lds(
      (const __attribute__((address_space(1))) unsigned*)g,
      (__attribute__((address_space(3))) unsigned*)l, 16, 0, 0);
}
__device__ __forceinline__ f32x4 mfma_bf16(short8 a, short8 b, f32x4 c) {
  return __builtin_amdgcn_mfma_f32_16x16x32_bf16(
      __builtin_bit_cast(bf16x8, a), __builtin_bit_cast(bf16x8, b), c, 0, 0, 0);
}

// ---------------- fp32 -> bf16 conversion (4 sources, contiguous dst) -------
#define CVT_N0 2097152
#define CVT_N1 6291456
#define CVT_N2 14680064
#define CVT_NT 16777216
__global__ __launch_bounds__(256) void cvt4_k(
    const float* __restrict__ s0, const float* __restrict__ s1,
    const float* __restrict__ s2, const float* __restrict__ s3,
    u16* __restrict__ out)
{
  int i = (blockIdx.x*256 + threadIdx.x) * 4;
  const float* src; int off;
  if (i < CVT_N0)      { src = s0; off = 0; }
  else if (i < CVT_N1) { src = s1; off = CVT_N0; }
  else if (i < CVT_N2) { src = s2; off = CVT_N1; }
  else                 { src = s3; off = CVT_N2; }
  float4 v = *(const float4*)(src + (i - off));
  ushort4 o;
  o.x = f2bf(v.x); o.y = f2bf(v.y); o.z = f2bf(v.z); o.w = f2bf(v.w);
  *(ushort4*)(out + i) = o;
}

// ---------------- bf16 MFMA GEMM (double-buffered) ----------------
// C[m,n] = sum_k A[m,k]*Bt[n,k].  A: M x K bf16, Bt: N x K bf16, K%64==0,
// M%128==0, N%128==0. Block: 512 thr (8 waves), tile 128x128, BK=64, 2 LDS bufs.
// EPI: 0 plain f32 out; 1 fusion gate (bf16 out); 2 residual add (f32 out);
//      3 spectral filter (bf16 out); 4 plain bf16 out.
template<int EPI>
__global__ __launch_bounds__(512) void mgemm_k(
    const u16* __restrict__ Ab, const u16* __restrict__ Bb,
    void* __restrict__ Cout, int K, int ldc,
    const float* __restrict__ aux0, const u16* __restrict__ aux1,
    const float* __restrict__ aux2, const float* __restrict__ aux3)
{
  __shared__ __align__(16) u16 As[2][128*64];
  __shared__ __align__(16) u16 Bs[2][128*64];
  const int t = threadIdx.x;
  const int lane = t & 63;
  const int w = t >> 6;                 // 0..7
  const int wm = w >> 2, wn = w & 3;    // wave sub-tile: rows 64*wm, cols 32*wn
  const int M0 = blockIdx.y * 128, N0 = blockIdx.x * 128;

  f32x4 acc[4][2] = {};

  // stage BK=64 K-slab into buffer `buf`
  auto stage = [&](int buf, int k0) {
    #pragma unroll
    for (int q = 0; q < 2; q++) {       // A tile: 1024 16B-units
      int u = q*512 + t;
      int row = u >> 3, gpr = u & 7;
      int grp = gpr ^ (row & 7);        // XOR swizzle
      gload16(Ab + (size_t)(M0+row)*K + k0 + grp*8, &As[buf][u*8]);
    }
    #pragma unroll
    for (int q = 0; q < 2; q++) {       // B tile
      int u = q*512 + t;
      int row = u >> 3, gpr = u & 7;
      int grp = gpr ^ (row & 7);
      gload16(Bb + (size_t)(N0+row)*K + k0 + grp*8, &Bs[buf][u*8]);
    }
  };

  stage(0, 0);
  const int nk = K >> 6;
  for (int ks = 0; ks < nk; ks++) {
    const int buf = ks & 1;
    __syncthreads();                    // drain stage(buf); protect buf^1 overwrite
    if (ks + 1 < nk) stage(buf ^ 1, (ks + 1) << 6);   // prefetch next slab
    const u16* Asb = As[buf];
    const u16* Bsb = Bs[buf];
    #pragma unroll
    for (int kk = 0; kk < 2; kk++) {
      const int quad = lane >> 4;
      const int grp = kk*4 + quad;
      short8 af[4], bf[2];
      #pragma unroll
      for (int i = 0; i < 4; i++) {
        int row = wm*64 + i*16 + (lane & 15);
        af[i] = *(const short8*)&Asb[(row*8 + (grp ^ (row & 7)))*8];
      }
      #pragma unroll
      for (int j = 0; j < 2; j++) {
        int row = wn*32 + j*16 + (lane & 15);
        bf[j] = *(const short8*)&Bsb[(row*8 + (grp ^ (row & 7)))*8];
      }
      #pragma unroll
      for (int i = 0; i < 4; i++)
        #pragma unroll
        for (int j = 0; j < 2; j++)
          acc[i][j] = mfma_bf16(af[i], bf[j], acc[i][j]);
    }
  }

  // C/D layout: col = lane&15, row = (lane>>4)*4 + r
  #pragma unroll
  for (int i = 0; i < 4; i++) {
    int mbase = M0 + wm*64 + i*16 + (lane >> 4)*4;
    #pragma unroll
    for (int j = 0; j < 2; j++) {
      int n = N0 + wn*32 + j*16 + (lane & 15);
      #pragma unroll
      for (int r = 0; r < 4; r++) {
        int m = mbase + r;
        float v = acc[i][j][r];
        if (EPI == 0) {
          ((float*)Cout)[(size_t)m*ldc + n] = v;
        } else if (EPI == 1) {          // fusion gate
          float g  = fsigm_(v + aux0[n]);
          float ys = bf2f(aux1[(size_t)m*4096 + n]);
          float yp = bf2f(aux1[(size_t)m*4096 + 2048 + n]);
          float z  = aux2[(size_t)m*4096 + 2048 + n];
          ((u16*)Cout)[(size_t)m*ldc + n] = f2bf((g*ys + (1.f-g)*yp)*fsilu_(z));
        } else if (EPI == 2) {          // residual add
          ((float*)Cout)[(size_t)m*ldc + n] = v + aux2[(size_t)m*ldc + n];
        } else if (EPI == 3) {          // spectral filter, complex pair via shfl
          float pv = __shfl_xor(v, 1, 64);
          int f = n >> 1;
          float outv = 0.f;
          if (f < NFFT_) {
            int c = m & (INNER_-1);
            float d  = fexp_(-aux2[c] * (float)f * (1.f/512.f));
            float wr = aux0[c*NFFT_+f]*d, wi = aux3[c*NFFT_+f]*d;
            float a = (n & 1) ? pv : v;
            float b = (n & 1) ? v : pv;
            outv = (n & 1) ? (a*wi + b*wr) : (a*wr - b*wi);
          }
          ((u16*)Cout)[(size_t)m*ldc + n] = f2bf(outv);
        } else {                        // 4: plain bf16
          ((u16*)Cout)[(size_t)m*ldc + n] = f2bf(v);
        }
      }
    }
  }
}

// ---------------- x_proj split-K: part[sk][m][40] = xconv[m, sk*64:+64] @ W^T ----
__global__ __launch_bounds__(256) void xproj_k(
    const float* __restrict__ xconv, const float* __restrict__ W,
    float* __restrict__ part)
{
  __shared__ float Bs[40][KSL_+4];
  const int sk = blockIdx.x, mt = blockIdx.y;
  const int k0 = sk*KSL_;
  for (int i = threadIdx.x; i < 40*KSL_; i += 256) {
    int n = i >> 6, k = i & (KSL_-1);
    Bs[n][k] = W[(size_t)n*2048 + k0 + k];
  }
  __syncthreads();
  const int m = mt*256 + threadIdx.x;
  const float* arow = xconv + (size_t)m*2048 + k0;
  float acc[40];
  #pragma unroll
  for (int j=0;j<40;j++) acc[j]=0.f;
  for (int k = 0; k < KSL_; k += 4) {
    float4 a = *(const float4*)(arow + k);
    #pragma unroll
    for (int j = 0; j < 40; j++) {
      float4 b = *(const float4*)&Bs[j][k];
      acc[j] += a.x*b.x + a.y*b.y + a.z*b.z + a.w*b.w;
    }
  }
  float* o = part + ((size_t)sk*M_ + m)*40;
  #pragma unroll
  for (int j = 0; j < 10; j++)
    *(float4*)(o + j*4) = make_float4(acc[j*4], acc[j*4+1], acc[j*4+2], acc[j*4+3]);
}

__global__ __launch_bounds__(256) void xpred_k(const float* __restrict__ part,
                                               float* __restrict__ xdbc)
{
  int i = blockIdx.x*256 + threadIdx.x;   // 81920 total
  float s = 0.f;
  #pragma unroll
  for (int sk = 0; sk < SK_; sk++) s += part[(size_t)sk*81920 + i];
  xdbc[i] = s;
}

// ---------------- depthwise causal conv(4) + silu ----------------
__global__ __launch_bounds__(256) void conv_silu_k(
    const float* __restrict__ xz, const float* __restrict__ cw,
    const float* __restrict__ cb, float* __restrict__ xc)
{
  int idx = blockIdx.x*256 + threadIdx.x;
  int c = idx & (INNER_-1);
  int m = idx >> 11;
  int l = m & (L_-1);
  const float* base = xz + (size_t)m*4096 + c;
  float w0=cw[c*4+0], w1=cw[c*4+1], w2=cw[c*4+2], w3=cw[c*4+3];
  float s = cb[c] + w3*base[0];
  if (l >= 1) s += w2*base[-4096];
  if (l >= 2) s += w1*base[-2*4096];
  if (l >= 3) s += w0*base[-3*4096];
  xc[(size_t)m*INNER_ + c] = fsilu_(s);
}

// ---------------- SSM chunked scan ----------------
// Pq layout per (b,ch,e): [0..15] = P (chunk transfer), [16..31] = q, then
// scan2 overwrites q-slot with h_in for that chunk.
__global__ __launch_bounds__(256) void scan1_k(
    const float* __restrict__ xdbc, const float* __restrict__ xconv,
    const float* __restrict__ A_log, const float* __restrict__ dtw,
    const float* __restrict__ dtb, float* __restrict__ Pq)
{
  int idx = blockIdx.x*256 + threadIdx.x;   // (b*NCH+ch)*INNER + e
  int e  = idx & (INNER_-1);
  int bc = idx >> 11;
  int ch = bc & (NCH_-1);
  int b  = bc >> 5;
  float A[STATE_];
  #pragma unroll
  for (int s=0;s<STATE_;s++) A[s] = -fexp_(A_log[e*STATE_+s]);
  float w[DTR_];
  #pragma unroll
  for (int r=0;r<DTR_;r++) w[r] = dtw[e*DTR_+r];
  float bias = dtb[e];
  float h[STATE_] = {};
  float sdt = 0.f;
  int mbase = b*L_ + ch*CHL_;
  for (int l=0;l<CHL_;l++) {
    int m = mbase + l;
    const float* row = xdbc + (size_t)m*40;
    float v = bias;
    #pragma unroll
    for (int r=0;r<DTR_;r++) v += row[r]*w[r];
    float dt = fsoftplus_(v);
    sdt += dt;
    float dx = dt * xconv[(size_t)m*INNER_ + e];
    #pragma unroll
    for (int s=0;s<STATE_;s++) {
      float dA = fexp_(dt*A[s]);
      h[s] = dA*h[s] + dx*row[8+s];
    }
  }
  float* o = Pq + (size_t)idx*32;
  #pragma unroll
  for (int s=0;s<STATE_;s++) { o[s] = fexp_(A[s]*sdt); o[16+s] = h[s]; }
}

// combine chunks, parallel over (b,e,s); h_in written into the q slot
__global__ __launch_bounds__(256) void scan2_k(float* __restrict__ Pq)
{
  int idx = blockIdx.x*256 + threadIdx.x;   // b*(INNER*16) + e*16 + s ; 65536
  int s = idx & 15;
  int e = (idx >> 4) & (INNER_-1);
  int b = idx >> 15;
  float h = 0.f;
  for (int ch = 0; ch < NCH_; ch++) {
    size_t base = ((size_t)(b*NCH_+ch)*INNER_ + e)*32;
    float p = Pq[base + s];
    float q = Pq[base + 16 + s];
    Pq[base + 16 + s] = h;
    h = p*h + q;
  }
}

__global__ __launch_bounds__(256) void scan3_k(
    const float* __restrict__ xdbc, const float* __restrict__ xconv,
    const float* __restrict__ A_log, const float* __restrict__ dtw,
    const float* __restrict__ dtb, const float* __restrict__ Dp,
    const float* __restrict__ Pq, u16* __restrict__ ycat)
{
  int idx = blockIdx.x*256 + threadIdx.x;
  int e  = idx & (INNER_-1);
  int bc = idx >> 11;
  int ch = bc & (NCH_-1);
  int b  = bc >> 5;
  float A[STATE_];
  #pragma unroll
  for (int s=0;s<STATE_;s++) A[s] = -fexp_(A_log[e*STATE_+s]);
  float w[DTR_];
  #pragma unroll
  for (int r=0;r<DTR_;r++) w[r] = dtw[e*DTR_+r];
  float bias = dtb[e];
  float Dv = Dp[e];
  float h[STATE_];
  const float* hi = Pq + (size_t)idx*32 + 16;
  #pragma unroll
  for (int s=0;s<STATE_;s++) h[s] = hi[s];
  int mbase = b*L_ + ch*CHL_;
  for (int l=0;l<CHL_;l++) {
    int m = mbase + l;
    const float* row = xdbc + (size_t)m*40;
    float v = bias;
    #pragma unroll
    for (int r=0;r<DTR_;r++) v += row[r]*w[r];
    float dt = fsoftplus_(v);
    float xcv = xconv[(size_t)m*INNER_ + e];
    float dx = dt * xcv;
    float y = 0.f;
    #pragma unroll
    for (int s=0;s<STATE_;s++) {
      float dA = fexp_(dt*A[s]);
      h[s] = dA*h[s] + dx*row[8+s];
      y += h[s]*row[24+s];
    }
    ycat[(size_t)m*4096 + e] = f2bf(y + xcv*Dv);
  }
}

// ---------------- transposes ----------------
__global__ __launch_bounds__(256) void transpose_fwd_k(const float* __restrict__ xz,
                                                       u16* __restrict__ xt)
{
  __shared__ float tile[32][33];
  int tx = threadIdx.x & 31, ty = threadIdx.x >> 5;
  int l0 = blockIdx.x*32, c0 = blockIdx.y*32, b = blockIdx.z;
  #pragma unroll
  for (int j=0;j<4;j++) {
    int l = l0 + ty + j*8;
    tile[ty+j*8][tx] = xz[(size_t)(b*L_+l)*4096 + (c0+tx)];
  }
  __syncthreads();
  #pragma unroll
  for (int j=0;j<4;j++) {
    int c = c0 + ty + j*8;
    xt[(size_t)(b*INNER_+c)*L_ + (l0+tx)] = f2bf(tile[tx][ty+j*8]);
  }
}

__global__ __launch_bounds__(256) void transpose_bwd_k(const u16* __restrict__ yt,
                                                       u16* __restrict__ ycat)
{
  __shared__ float tile[32][33];
  int tx = threadIdx.x & 31, ty = threadIdx.x >> 5;
  int l0 = blockIdx.x*32, c0 = blockIdx.y*32, b = blockIdx.z;
  #pragma unroll
  for (int j=0;j<4;j++) {
    int c = c0 + ty + j*8;
    tile[ty+j*8][tx] = bf2f(yt[(size_t)(b*INNER_+c)*L_ + (l0+tx)]);
  }
  __syncthreads();
  #pragma unroll
  for (int j=0;j<4;j++) {
    int l = l0 + ty + j*8;
    ycat[(size_t)(b*L_+l)*4096 + 2048 + (c0+tx)] = f2bf(tile[tx][ty+j*8]);
  }
}

// ---------------- DFT matrix generation (bf16, K-contiguous) ----------------
__global__ __launch_bounds__(256) void genWdftb_k(u16* __restrict__ W) {
  int idx = blockIdx.x*256 + threadIdx.x;  // col*1024 + l ; col < NFP_
  int l = idx & (L_-1);
  int col = idx >> 10;
  float v = 0.f;
  int f = col >> 1;
  if (f < NFFT_) {
    int ph = (l*f) & (L_-1);
    float th = (float)ph * (6.283185307179586f / (float)L_);
    v = (col & 1) ? -__sinf(th) : __cosf(th);
  }
  W[idx] = f2bf(v);
}

__global__ __launch_bounds__(256) void genWinvb_k(u16* __restrict__ W) {
  int idx = blockIdx.x*256 + threadIdx.x;  // l*NFP_ + r
  int r = idx % NFP_;
  int l = idx / NFP_;
  int f = r >> 1;
  float v = 0.f;
  if (f < NFFT_) {
    bool edge = (f == 0) || (f == 512);
    float sc = (edge ? 1.f : 2.f) / (float)L_;
    int ph = (f*l) & (L_-1);
    float th = (float)ph * (6.283185307179586f / (float)L_);
    if (r & 1) v = edge ? 0.f : -sc*__sinf(th);
    else       v = sc*__cosf(th);
  }
  W[idx] = f2bf(v);
}

// ---------------- layernorm ----------------
__global__ __launch_bounds__(256) void ln_k(const float* __restrict__ inp,
    const float* __restrict__ gma, const float* __restrict__ bta,
    float* __restrict__ out)
{
  int m = blockIdx.x;
  const float* row = inp + (size_t)m*DM_;
  float s=0.f, s2=0.f;
  float v[4];
  #pragma unroll
  for (int j=0;j<4;j++) {
    v[j] = row[threadIdx.x + j*256];
    s += v[j]; s2 += v[j]*v[j];
  }
  #pragma unroll
  for (int off=32; off>=1; off>>=1) {
    s  += __shfl_down(s, off);
    s2 += __shfl_down(s2, off);
  }
  __shared__ float rs[4], rs2[4], stats[2];
  int wid = threadIdx.x >> 6;
  if ((threadIdx.x & 63) == 0) { rs[wid]=s; rs2[wid]=s2; }
  __syncthreads();
  if (threadIdx.x == 0) {
    float ts  = rs[0]+rs[1]+rs[2]+rs[3];
    float ts2 = rs2[0]+rs2[1]+rs2[2]+rs2[3];
    float mu  = ts/(float)DM_;
    float var = ts2/(float)DM_ - mu*mu;
    stats[0] = mu; stats[1] = rsqrtf(var + 1e-5f);
  }
  __syncthreads();
  float mu = stats[0], rstd = stats[1];
  #pragma unroll
  for (int j=0;j<4;j++) {
    int n = threadIdx.x + j*256;
    out[(size_t)m*DM_ + n] = (v[j]-mu)*rstd*gma[n] + bta[n];
  }
}

extern "C" void kernel_launch(void* const* d_in, const int* in_sizes, int n_in,
                              void* d_out, int out_size, void* d_ws, size_t ws_size,
                              hipStream_t stream)
{
  const float* x       = (const float*)d_in[0];
  const float* in_w    = (const float*)d_in[1];
  const float* conv_w  = (const float*)d_in[2];
  const float* conv_b  = (const float*)d_in[3];
  const float* A_log   = (const float*)d_in[4];
  const float* Dp      = (const float*)d_in[5];
  const float* xproj_w = (const float*)d_in[6];
  const float* dt_w    = (const float*)d_in[7];
  const float* dt_b    = (const float*)d_in[8];
  const float* f_re    = (const float*)d_in[9];
  const float* f_im    = (const float*)d_in[10];
  const float* s_dec   = (const float*)d_in[11];
  const float* fus_w   = (const float*)d_in[12];
  const float* fus_b   = (const float*)d_in[13];
  const float* out_w   = (const float*)d_in[14];
  const float* ln_g    = (const float*)d_in[15];
  const float* ln_b    = (const float*)d_in[16];
  float* out = (float*)d_out;

  // ---- workspace carve (fp32 region then bf16 region), ~138 MB total ----
  float* ws    = (float*)d_ws;
  float* xz    = ws;                       // 8388608  (M x 4096)
  float* xconv = xz    + 8388608;          // 4194304  (M x 2048), reused as outp
  float* xdbc  = xconv + 4194304;          // 81920    (M x 40)
  float* Pq    = xdbc  + 81920;            // 4194304  (B*NCH*INNER x 32), holds h_in too
  u16* ub      = (u16*)(Pq + 4194304);
  u16* xb      = ub;                       // 2097152   x bf16
  u16* inwb    = xb    + 2097152;          // 4194304   in_w bf16; reused as yt
  u16* fuswb   = inwb  + 4194304;          // 8388608   fus_w bf16
  u16* outwb   = fuswb + 8388608;          // 2097152   out_w bf16
  u16* xt      = outwb + 2097152;          // 4194304   x_inner^T bf16; reused as ycomb
  u16* Wb      = xt    + 4194304;          // 1179648   Wdft then Winv
  u16* XFb     = Wb    + 1179648;          // 4718592   (MD x NFP) bf16
  u16* ycat    = XFb   + 4718592;          // 8388608   (M x 4096) bf16
  u16* yt      = inwb;
  u16* ycomb   = xt;
  float* outp  = xconv;
  float* part  = (float*)ycat;             // 2.6M floats, dead before scan3 writes ycat

  // 0. convert GEMM operands to bf16 (xb,inwb,fuswb,outwb are contiguous)
  cvt4_k<<<CVT_NT/1024, 256, 0, stream>>>(x, in_w, fus_w, out_w, xb);

  // 1. xz = x @ in_proj_w^T   (2048 x 4096 x 1024) MFMA
  mgemm_k<0><<<dim3(4096/128, M_/128), 512, 0, stream>>>(
      xb, inwb, xz, 1024, 4096, nullptr, nullptr, nullptr, nullptr);
  // 2. depthwise conv + silu
  conv_silu_k<<<(M_*INNER_)/256, 256, 0, stream>>>(xz, conv_w, conv_b, xconv);
  // 3. x_dbc = x_conv @ x_proj_w^T  (2048 x 40 x 2048) split-K fp32
  xproj_k<<<dim3(SK_, M_/256), 256, 0, stream>>>(xconv, xproj_w, part);
  xpred_k<<<(M_*40)/256, 256, 0, stream>>>(part, xdbc);
  // 4-6. chunked SSM scan -> y_cat[:, :2048] (bf16)
  scan1_k<<<(B_*NCH_*INNER_)/256, 256, 0, stream>>>(xdbc, xconv, A_log, dt_w, dt_b, Pq);
  scan2_k<<<(B_*INNER_*STATE_)/256, 256, 0, stream>>>(Pq);
  scan3_k<<<(B_*NCH_*INNER_)/256, 256, 0, stream>>>(xdbc, xconv, A_log, dt_w, dt_b, Dp, Pq, ycat);
  // 7. transpose x_inner -> (b,c,l) bf16
  transpose_fwd_k<<<dim3(L_/32, INNER_/32, B_), 256, 0, stream>>>(xz, xt);
  // 8. forward DFT + fused spectral filter: XFb = filt(xt @ Wdft)
  genWdftb_k<<<(NFP_*1024)/256, 256, 0, stream>>>(Wb);
  mgemm_k<3><<<dim3(NFP_/128, MD_/128), 512, 0, stream>>>(
      xt, Wb, XFb, 1024, NFP_, f_re, nullptr, s_dec, f_im);
  // 9. inverse DFT: yt = XFb @ Winv  (4096 x 1024 x 1152) -> bf16
  genWinvb_k<<<(NFP_*1024)/256, 256, 0, stream>>>(Wb);
  mgemm_k<4><<<dim3(1024/128, MD_/128), 512, 0, stream>>>(
      XFb, Wb, yt, NFP_, 1024, nullptr, nullptr, nullptr, nullptr);
  // 10. transpose back -> y_cat[:, 2048:]
  transpose_bwd_k<<<dim3(L_/32, INNER_/32, B_), 256, 0, stream>>>(yt, ycat);
  // 11. fusion GEMM + gate epilogue (2048 x 2048 x 4096) -> ycomb bf16
  mgemm_k<1><<<dim3(2048/128, M_/128), 512, 0, stream>>>(
      ycat, fuswb, ycomb, 4096, 2048, fus_b, ycat, xz, nullptr);
  // 12. out proj + residual (2048 x 1024 x 2048) -> fp32
  mgemm_k<2><<<dim3(1024/128, M_/128), 512, 0, stream>>>(
      ycomb, outwb, outp, 2048, 1024, nullptr, nullptr, x, nullptr);
  // 13. layernorm -> d_out
  ln_k<<<M_, 256, 0, stream>>>(outp, ln_g, ln_b, out);
}

// Round 6
// 443.222 us; speedup vs baseline: 3.8182x; 1.0486x over previous
//
#include <hip/hip_runtime.h>
#include <math.h>

#define B_ 2
#define L_ 1024
#define DM_ 1024
#define STATE_ 16
#define CONV_ 4
#define DTR_ 8
#define INNER_ 2048
#define M_ (B_*L_)        /* 2048 rows (b,l) */
#define MD_ (B_*INNER_)   /* 4096 rows (b,c) */
#define NFFT_ 513
#define NFP_ 1152         /* 2*513=1026 padded to multiple of 128 */
#define NCH_ 32
#define CHL_ 32
#define SK_ 32            /* x_proj split-K factor */
#define KSL_ (2048/SK_)   /* 64 */

typedef unsigned short u16;
typedef __attribute__((ext_vector_type(8))) short short8;
typedef __attribute__((ext_vector_type(8))) __bf16 bf16x8;
typedef __attribute__((ext_vector_type(4))) float f32x4;

__device__ __forceinline__ float frcp_(float x) { return __builtin_amdgcn_rcpf(x); }
__device__ __forceinline__ float fexp_(float x) { return __expf(x); }
__device__ __forceinline__ float fsigm_(float x) { return frcp_(1.f + __expf(-x)); }
__device__ __forceinline__ float fsilu_(float x) { return x * frcp_(1.f + __expf(-x)); }
__device__ __forceinline__ float fsoftplus_(float v) {
  return (v > 20.f) ? v : __logf(1.f + __expf(v));
}
__device__ __forceinline__ u16 f2bf(float f) {
  union { float f; unsigned u; } v; v.f = f;
  unsigned r = v.u + 0x7fffu + ((v.u >> 16) & 1u);
  return (u16)(r >> 16);
}
__device__ __forceinline__ float bf2f(u16 h) {
  union { unsigned u; float f; } v; v.u = ((unsigned)h) << 16;
  return v.f;
}
__device__ __forceinline__ void gload16(const void* g, void* l) {
  __builtin_amdgcn_global_load_lds(
      (const __attribute__((address_space(1))) unsigned*)g,
      (__attribute__((address_space(3))) unsigned*)l, 16, 0, 0);
}
__device__ __forceinline__ f32x4 mfma_bf16(short8 a, short8 b, f32x4 c) {
  return __builtin_amdgcn_mfma_f32_16x16x32_bf16(
      __builtin_bit_cast(bf16x8, a), __builtin_bit_cast(bf16x8, b), c, 0, 0, 0);
}

// ---------------- fp32 -> bf16 conversion (4 sources, contiguous dst) -------
#define CVT_N0 2097152
#define CVT_N1 6291456
#define CVT_N2 14680064
#define CVT_NT 16777216
__global__ __launch_bounds__(256) void cvt4_k(
    const float* __restrict__ s0, const float* __restrict__ s1,
    const float* __restrict__ s2, const float* __restrict__ s3,
    u16* __restrict__ out)
{
  int i = (blockIdx.x*256 + threadIdx.x) * 4;
  const float* src; int off;
  if (i < CVT_N0)      { src = s0; off = 0; }
  else if (i < CVT_N1) { src = s1; off = CVT_N0; }
  else if (i < CVT_N2) { src = s2; off = CVT_N1; }
  else                 { src = s3; off = CVT_N2; }
  float4 v = *(const float4*)(src + (i - off));
  ushort4 o;
  o.x = f2bf(v.x); o.y = f2bf(v.y); o.z = f2bf(v.z); o.w = f2bf(v.w);
  *(ushort4*)(out + i) = o;
}

// ---------------- bf16 MFMA GEMM (templated tile, double-buffered) ----------
// C[m,n] = sum_k A[m,k]*Bt[n,k].  A: M x K bf16, Bt: N x K bf16, K%64==0,
// M%TM==0, N%TN==0. Wave sub-tile 64x32 (acc 4x2); waves = (TM/64)*(TN/32).
// EPI: 0 plain f32 out; 1 fusion gate (bf16 out); 2 residual add (f32 out);
//      3 spectral filter (bf16 out); 4 plain bf16 out.
template<int TM, int TN, int EPI>
__global__ __launch_bounds__((TM/64)*(TN/32)*64) void mgemm_k(
    const u16* __restrict__ Ab, const u16* __restrict__ Bb,
    void* __restrict__ Cout, int K, int ldc,
    const float* __restrict__ aux0, const u16* __restrict__ aux1,
    const float* __restrict__ aux2, const float* __restrict__ aux3)
{
  constexpr int WN   = TN/32;
  constexpr int NW   = (TM/64)*WN;
  constexpr int NTHR = NW*64;
  __shared__ __align__(16) u16 As[2][TM*64];
  __shared__ __align__(16) u16 Bs[2][TN*64];
  const int t = threadIdx.x;
  const int lane = t & 63;
  const int w = t >> 6;
  const int wm = w / WN, wn = w % WN;
  const int M0 = blockIdx.y * TM, N0 = blockIdx.x * TN;

  f32x4 acc[4][2] = {};

  auto stage = [&](int buf, int k0) {
    #pragma unroll
    for (int q = 0; q < TM*8/NTHR; q++) {
      int u = q*NTHR + t;
      int row = u >> 3, gpr = u & 7;
      int grp = gpr ^ (row & 7);        // XOR swizzle
      gload16(Ab + (size_t)(M0+row)*K + k0 + grp*8, &As[buf][u*8]);
    }
    #pragma unroll
    for (int q = 0; q < TN*8/NTHR; q++) {
      int u = q*NTHR + t;
      int row = u >> 3, gpr = u & 7;
      int grp = gpr ^ (row & 7);
      gload16(Bb + (size_t)(N0+row)*K + k0 + grp*8, &Bs[buf][u*8]);
    }
  };

  stage(0, 0);
  const int nk = K >> 6;
  for (int ks = 0; ks < nk; ks++) {
    const int buf = ks & 1;
    __syncthreads();                    // drain stage(buf); protect buf^1 overwrite
    if (ks + 1 < nk) stage(buf ^ 1, (ks + 1) << 6);
    const u16* Asb = As[buf];
    const u16* Bsb = Bs[buf];
    #pragma unroll
    for (int kk = 0; kk < 2; kk++) {
      const int quad = lane >> 4;
      const int grp = kk*4 + quad;
      short8 af[4], bf[2];
      #pragma unroll
      for (int i = 0; i < 4; i++) {
        int row = wm*64 + i*16 + (lane & 15);
        af[i] = *(const short8*)&Asb[(row*8 + (grp ^ (row & 7)))*8];
      }
      #pragma unroll
      for (int j = 0; j < 2; j++) {
        int row = wn*32 + j*16 + (lane & 15);
        bf[j] = *(const short8*)&Bsb[(row*8 + (grp ^ (row & 7)))*8];
      }
      #pragma unroll
      for (int i = 0; i < 4; i++)
        #pragma unroll
        for (int j = 0; j < 2; j++)
          acc[i][j] = mfma_bf16(af[i], bf[j], acc[i][j]);
    }
  }

  // C/D layout: col = lane&15, row = (lane>>4)*4 + r
  #pragma unroll
  for (int i = 0; i < 4; i++) {
    int mbase = M0 + wm*64 + i*16 + (lane >> 4)*4;
    #pragma unroll
    for (int j = 0; j < 2; j++) {
      int n = N0 + wn*32 + j*16 + (lane & 15);
      #pragma unroll
      for (int r = 0; r < 4; r++) {
        int m = mbase + r;
        float v = acc[i][j][r];
        if (EPI == 0) {
          ((float*)Cout)[(size_t)m*ldc + n] = v;
        } else if (EPI == 1) {          // fusion gate
          float g  = fsigm_(v + aux0[n]);
          float ys = bf2f(aux1[(size_t)m*4096 + n]);
          float yp = bf2f(aux1[(size_t)m*4096 + 2048 + n]);
          float z  = aux2[(size_t)m*4096 + 2048 + n];
          ((u16*)Cout)[(size_t)m*ldc + n] = f2bf((g*ys + (1.f-g)*yp)*fsilu_(z));
        } else if (EPI == 2) {          // residual add
          ((float*)Cout)[(size_t)m*ldc + n] = v + aux2[(size_t)m*ldc + n];
        } else if (EPI == 3) {          // spectral filter, complex pair via shfl
          float pv = __shfl_xor(v, 1, 64);
          int f = n >> 1;
          float outv = 0.f;
          if (f < NFFT_) {
            int c = m & (INNER_-1);
            float d  = fexp_(-aux2[c] * (float)f * (1.f/512.f));
            float wr = aux0[c*NFFT_+f]*d, wi = aux3[c*NFFT_+f]*d;
            float a = (n & 1) ? pv : v;
            float b = (n & 1) ? v : pv;
            outv = (n & 1) ? (a*wi + b*wr) : (a*wr - b*wi);
          }
          ((u16*)Cout)[(size_t)m*ldc + n] = f2bf(outv);
        } else {                        // 4: plain bf16
          ((u16*)Cout)[(size_t)m*ldc + n] = f2bf(v);
        }
      }
    }
  }
}

// ---------------- x_proj split-K: part[sk][m][40] = xconv[m, sk*64:+64] @ W^T ----
__global__ __launch_bounds__(256) void xproj_k(
    const float* __restrict__ xconv, const float* __restrict__ W,
    float* __restrict__ part)
{
  __shared__ float Bs[40][KSL_+4];
  const int sk = blockIdx.x, mt = blockIdx.y;
  const int k0 = sk*KSL_;
  for (int i = threadIdx.x; i < 40*KSL_; i += 256) {
    int n = i >> 6, k = i & (KSL_-1);
    Bs[n][k] = W[(size_t)n*2048 + k0 + k];
  }
  __syncthreads();
  const int m = mt*256 + threadIdx.x;
  const float* arow = xconv + (size_t)m*2048 + k0;
  float acc[40];
  #pragma unroll
  for (int j=0;j<40;j++) acc[j]=0.f;
  for (int k = 0; k < KSL_; k += 4) {
    float4 a = *(const float4*)(arow + k);
    #pragma unroll
    for (int j = 0; j < 40; j++) {
      float4 b = *(const float4*)&Bs[j][k];
      acc[j] += a.x*b.x + a.y*b.y + a.z*b.z + a.w*b.w;
    }
  }
  float* o = part + ((size_t)sk*M_ + m)*40;
  #pragma unroll
  for (int j = 0; j < 10; j++)
    *(float4*)(o + j*4) = make_float4(acc[j*4], acc[j*4+1], acc[j*4+2], acc[j*4+3]);
}

__global__ __launch_bounds__(256) void xpred_k(const float* __restrict__ part,
                                               float* __restrict__ xdbc)
{
  int i = blockIdx.x*256 + threadIdx.x;   // 81920 total
  float s = 0.f;
  #pragma unroll
  for (int sk = 0; sk < SK_; sk++) s += part[(size_t)sk*81920 + i];
  xdbc[i] = s;
}

// ---------------- depthwise causal conv(4) + silu ----------------
__global__ __launch_bounds__(256) void conv_silu_k(
    const float* __restrict__ xz, const float* __restrict__ cw,
    const float* __restrict__ cb, float* __restrict__ xc)
{
  int idx = blockIdx.x*256 + threadIdx.x;
  int c = idx & (INNER_-1);
  int m = idx >> 11;
  int l = m & (L_-1);
  const float* base = xz + (size_t)m*4096 + c;
  float w0=cw[c*4+0], w1=cw[c*4+1], w2=cw[c*4+2], w3=cw[c*4+3];
  float s = cb[c] + w3*base[0];
  if (l >= 1) s += w2*base[-4096];
  if (l >= 2) s += w1*base[-2*4096];
  if (l >= 3) s += w0*base[-3*4096];
  xc[(size_t)m*INNER_ + c] = fsilu_(s);
}

// ---------------- SSM chunked scan ----------------
// Pq layout per (b,ch,e): [0..15] = P (chunk transfer), [16..31] = q, then
// scan2 overwrites q-slot with h_in for that chunk.
__global__ __launch_bounds__(256) void scan1_k(
    const float* __restrict__ xdbc, const float* __restrict__ xconv,
    const float* __restrict__ A_log, const float* __restrict__ dtw,
    const float* __restrict__ dtb, float* __restrict__ Pq)
{
  int idx = blockIdx.x*256 + threadIdx.x;   // (b*NCH+ch)*INNER + e
  int e  = idx & (INNER_-1);
  int bc = idx >> 11;
  int ch = bc & (NCH_-1);
  int b  = bc >> 5;
  float A[STATE_];
  #pragma unroll
  for (int s=0;s<STATE_;s++) A[s] = -fexp_(A_log[e*STATE_+s]);
  float w[DTR_];
  #pragma unroll
  for (int r=0;r<DTR_;r++) w[r] = dtw[e*DTR_+r];
  float bias = dtb[e];
  float h[STATE_] = {};
  float sdt = 0.f;
  int mbase = b*L_ + ch*CHL_;
  for (int l=0;l<CHL_;l++) {
    int m = mbase + l;
    const float* row = xdbc + (size_t)m*40;
    float v = bias;
    #pragma unroll
    for (int r=0;r<DTR_;r++) v += row[r]*w[r];
    float dt = fsoftplus_(v);
    sdt += dt;
    float dx = dt * xconv[(size_t)m*INNER_ + e];
    #pragma unroll
    for (int s=0;s<STATE_;s++) {
      float dA = fexp_(dt*A[s]);
      h[s] = dA*h[s] + dx*row[8+s];
    }
  }
  float* o = Pq + (size_t)idx*32;
  #pragma unroll
  for (int s=0;s<STATE_;s++) { o[s] = fexp_(A[s]*sdt); o[16+s] = h[s]; }
}

// combine chunks, parallel over (b,e,s); h_in written into the q slot
__global__ __launch_bounds__(256) void scan2_k(float* __restrict__ Pq)
{
  int idx = blockIdx.x*256 + threadIdx.x;   // b*(INNER*16) + e*16 + s ; 65536
  int s = idx & 15;
  int e = (idx >> 4) & (INNER_-1);
  int b = idx >> 15;
  float h = 0.f;
  for (int ch = 0; ch < NCH_; ch++) {
    size_t base = ((size_t)(b*NCH_+ch)*INNER_ + e)*32;
    float p = Pq[base + s];
    float q = Pq[base + 16 + s];
    Pq[base + 16 + s] = h;
    h = p*h + q;
  }
}

__global__ __launch_bounds__(256) void scan3_k(
    const float* __restrict__ xdbc, const float* __restrict__ xconv,
    const float* __restrict__ A_log, const float* __restrict__ dtw,
    const float* __restrict__ dtb, const float* __restrict__ Dp,
    const float* __restrict__ Pq, u16* __restrict__ ycat)
{
  int idx = blockIdx.x*256 + threadIdx.x;
  int e  = idx & (INNER_-1);
  int bc = idx >> 11;
  int ch = bc & (NCH_-1);
  int b  = bc >> 5;
  float A[STATE_];
  #pragma unroll
  for (int s=0;s<STATE_;s++) A[s] = -fexp_(A_log[e*STATE_+s]);
  float w[DTR_];
  #pragma unroll
  for (int r=0;r<DTR_;r++) w[r] = dtw[e*DTR_+r];
  float bias = dtb[e];
  float Dv = Dp[e];
  float h[STATE_];
  const float* hi = Pq + (size_t)idx*32 + 16;
  #pragma unroll
  for (int s=0;s<STATE_;s++) h[s] = hi[s];
  int mbase = b*L_ + ch*CHL_;
  for (int l=0;l<CHL_;l++) {
    int m = mbase + l;
    const float* row = xdbc + (size_t)m*40;
    float v = bias;
    #pragma unroll
    for (int r=0;r<DTR_;r++) v += row[r]*w[r];
    float dt = fsoftplus_(v);
    float xcv = xconv[(size_t)m*INNER_ + e];
    float dx = dt * xcv;
    float y = 0.f;
    #pragma unroll
    for (int s=0;s<STATE_;s++) {
      float dA = fexp_(dt*A[s]);
      h[s] = dA*h[s] + dx*row[8+s];
      y += h[s]*row[24+s];
    }
    ycat[(size_t)m*4096 + e] = f2bf(y + xcv*Dv);
  }
}

// ---------------- transposes ----------------
__global__ __launch_bounds__(256) void transpose_fwd_k(const float* __restrict__ xz,
                                                       u16* __restrict__ xt)
{
  __shared__ float tile[32][33];
  int tx = threadIdx.x & 31, ty = threadIdx.x >> 5;
  int l0 = blockIdx.x*32, c0 = blockIdx.y*32, b = blockIdx.z;
  #pragma unroll
  for (int j=0;j<4;j++) {
    int l = l0 + ty + j*8;
    tile[ty+j*8][tx] = xz[(size_t)(b*L_+l)*4096 + (c0+tx)];
  }
  __syncthreads();
  #pragma unroll
  for (int j=0;j<4;j++) {
    int c = c0 + ty + j*8;
    xt[(size_t)(b*INNER_+c)*L_ + (l0+tx)] = f2bf(tile[tx][ty+j*8]);
  }
}

__global__ __launch_bounds__(256) void transpose_bwd_k(const u16* __restrict__ yt,
                                                       u16* __restrict__ ycat)
{
  __shared__ float tile[32][33];
  int tx = threadIdx.x & 31, ty = threadIdx.x >> 5;
  int l0 = blockIdx.x*32, c0 = blockIdx.y*32, b = blockIdx.z;
  #pragma unroll
  for (int j=0;j<4;j++) {
    int c = c0 + ty + j*8;
    tile[ty+j*8][tx] = bf2f(yt[(size_t)(b*INNER_+c)*L_ + (l0+tx)]);
  }
  __syncthreads();
  #pragma unroll
  for (int j=0;j<4;j++) {
    int l = l0 + ty + j*8;
    ycat[(size_t)(b*L_+l)*4096 + 2048 + (c0+tx)] = f2bf(tile[tx][ty+j*8]);
  }
}

// ---------------- DFT matrix generation (bf16, K-contiguous) ----------------
__global__ __launch_bounds__(256) void genWdftb_k(u16* __restrict__ W) {
  int idx = blockIdx.x*256 + threadIdx.x;  // col*1024 + l ; col < NFP_
  int l = idx & (L_-1);
  int col = idx >> 10;
  float v = 0.f;
  int f = col >> 1;
  if (f < NFFT_) {
    int ph = (l*f) & (L_-1);
    float th = (float)ph * (6.283185307179586f / (float)L_);
    v = (col & 1) ? -__sinf(th) : __cosf(th);
  }
  W[idx] = f2bf(v);
}

__global__ __launch_bounds__(256) void genWinvb_k(u16* __restrict__ W) {
  int idx = blockIdx.x*256 + threadIdx.x;  // l*NFP_ + r
  int r = idx % NFP_;
  int l = idx / NFP_;
  int f = r >> 1;
  float v = 0.f;
  if (f < NFFT_) {
    bool edge = (f == 0) || (f == 512);
    float sc = (edge ? 1.f : 2.f) / (float)L_;
    int ph = (f*l) & (L_-1);
    float th = (float)ph * (6.283185307179586f / (float)L_);
    if (r & 1) v = edge ? 0.f : -sc*__sinf(th);
    else       v = sc*__cosf(th);
  }
  W[idx] = f2bf(v);
}

// ---------------- layernorm ----------------
__global__ __launch_bounds__(256) void ln_k(const float* __restrict__ inp,
    const float* __restrict__ gma, const float* __restrict__ bta,
    float* __restrict__ out)
{
  int m = blockIdx.x;
  const float* row = inp + (size_t)m*DM_;
  float s=0.f, s2=0.f;
  float v[4];
  #pragma unroll
  for (int j=0;j<4;j++) {
    v[j] = row[threadIdx.x + j*256];
    s += v[j]; s2 += v[j]*v[j];
  }
  #pragma unroll
  for (int off=32; off>=1; off>>=1) {
    s  += __shfl_down(s, off);
    s2 += __shfl_down(s2, off);
  }
  __shared__ float rs[4], rs2[4], stats[2];
  int wid = threadIdx.x >> 6;
  if ((threadIdx.x & 63) == 0) { rs[wid]=s; rs2[wid]=s2; }
  __syncthreads();
  if (threadIdx.x == 0) {
    float ts  = rs[0]+rs[1]+rs[2]+rs[3];
    float ts2 = rs2[0]+rs2[1]+rs2[2]+rs2[3];
    float mu  = ts/(float)DM_;
    float var = ts2/(float)DM_ - mu*mu;
    stats[0] = mu; stats[1] = rsqrtf(var + 1e-5f);
  }
  __syncthreads();
  float mu = stats[0], rstd = stats[1];
  #pragma unroll
  for (int j=0;j<4;j++) {
    int n = threadIdx.x + j*256;
    out[(size_t)m*DM_ + n] = (v[j]-mu)*rstd*gma[n] + bta[n];
  }
}

extern "C" void kernel_launch(void* const* d_in, const int* in_sizes, int n_in,
                              void* d_out, int out_size, void* d_ws, size_t ws_size,
                              hipStream_t stream)
{
  const float* x       = (const float*)d_in[0];
  const float* in_w    = (const float*)d_in[1];
  const float* conv_w  = (const float*)d_in[2];
  const float* conv_b  = (const float*)d_in[3];
  const float* A_log   = (const float*)d_in[4];
  const float* Dp      = (const float*)d_in[5];
  const float* xproj_w = (const float*)d_in[6];
  const float* dt_w    = (const float*)d_in[7];
  const float* dt_b    = (const float*)d_in[8];
  const float* f_re    = (const float*)d_in[9];
  const float* f_im    = (const float*)d_in[10];
  const float* s_dec   = (const float*)d_in[11];
  const float* fus_w   = (const float*)d_in[12];
  const float* fus_b   = (const float*)d_in[13];
  const float* out_w   = (const float*)d_in[14];
  const float* ln_g    = (const float*)d_in[15];
  const float* ln_b    = (const float*)d_in[16];
  float* out = (float*)d_out;

  // ---- workspace carve (fp32 region then bf16 region), ~138 MB total ----
  float* ws    = (float*)d_ws;
  float* xz    = ws;                       // 8388608  (M x 4096)
  float* xconv = xz    + 8388608;          // 4194304  (M x 2048), reused as outp
  float* xdbc  = xconv + 4194304;          // 81920    (M x 40)
  float* Pq    = xdbc  + 81920;            // 4194304  (B*NCH*INNER x 32), holds h_in too
  u16* ub      = (u16*)(Pq + 4194304);
  u16* xb      = ub;                       // 2097152   x bf16
  u16* inwb    = xb    + 2097152;          // 4194304   in_w bf16; reused as yt
  u16* fuswb   = inwb  + 4194304;          // 8388608   fus_w bf16
  u16* outwb   = fuswb + 8388608;          // 2097152   out_w bf16
  u16* xt      = outwb + 2097152;          // 4194304   x_inner^T bf16; reused as ycomb
  u16* Wb      = xt    + 4194304;          // 1179648   Wdft then Winv
  u16* XFb     = Wb    + 1179648;          // 4718592   (MD x NFP) bf16
  u16* ycat    = XFb   + 4718592;          // 8388608   (M x 4096) bf16
  u16* yt      = inwb;
  u16* ycomb   = xt;
  float* outp  = xconv;
  float* part  = (float*)ycat;             // 2.6M floats, dead before scan3 writes ycat

  // 0. convert GEMM operands to bf16 (xb,inwb,fuswb,outwb are contiguous)
  cvt4_k<<<CVT_NT/1024, 256, 0, stream>>>(x, in_w, fus_w, out_w, xb);

  // 1. xz = x @ in_proj_w^T   (2048 x 4096 x 1024) MFMA, 512 blocks
  mgemm_k<128,128,0><<<dim3(4096/128, M_/128), 512, 0, stream>>>(
      xb, inwb, xz, 1024, 4096, nullptr, nullptr, nullptr, nullptr);
  // 2. depthwise conv + silu
  conv_silu_k<<<(M_*INNER_)/256, 256, 0, stream>>>(xz, conv_w, conv_b, xconv);
  // 3. x_dbc = x_conv @ x_proj_w^T  (2048 x 40 x 2048) split-K fp32
  xproj_k<<<dim3(SK_, M_/256), 256, 0, stream>>>(xconv, xproj_w, part);
  xpred_k<<<(M_*40)/256, 256, 0, stream>>>(part, xdbc);
  // 4-6. chunked SSM scan -> y_cat[:, :2048] (bf16)
  scan1_k<<<(B_*NCH_*INNER_)/256, 256, 0, stream>>>(xdbc, xconv, A_log, dt_w, dt_b, Pq);
  scan2_k<<<(B_*INNER_*STATE_)/256, 256, 0, stream>>>(Pq);
  scan3_k<<<(B_*NCH_*INNER_)/256, 256, 0, stream>>>(xdbc, xconv, A_log, dt_w, dt_b, Dp, Pq, ycat);
  // 7. transpose x_inner -> (b,c,l) bf16
  transpose_fwd_k<<<dim3(L_/32, INNER_/32, B_), 256, 0, stream>>>(xz, xt);
  // 8. forward DFT + fused spectral filter: XFb = filt(xt @ Wdft), 576 blocks
  genWdftb_k<<<(NFP_*1024)/256, 256, 0, stream>>>(Wb);
  mgemm_k<128,64,3><<<dim3(NFP_/64, MD_/128), 256, 0, stream>>>(
      xt, Wb, XFb, 1024, NFP_, f_re, nullptr, s_dec, f_im);
  // 9. inverse DFT: yt = XFb @ Winv  (4096 x 1024 x 1152) -> bf16, 512 blocks
  genWinvb_k<<<(NFP_*1024)/256, 256, 0, stream>>>(Wb);
  mgemm_k<128,64,4><<<dim3(1024/64, MD_/128), 256, 0, stream>>>(
      XFb, Wb, yt, NFP_, 1024, nullptr, nullptr, nullptr, nullptr);
  // 10. transpose back -> y_cat[:, 2048:]
  transpose_bwd_k<<<dim3(L_/32, INNER_/32, B_), 256, 0, stream>>>(yt, ycat);
  // 11. fusion GEMM + gate epilogue (2048 x 2048 x 4096) -> ycomb bf16, 512 blocks
  mgemm_k<128,64,1><<<dim3(2048/64, M_/128), 256, 0, stream>>>(
      ycat, fuswb, ycomb, 4096, 2048, fus_b, ycat, xz, nullptr);
  // 12. out proj + residual (2048 x 1024 x 2048) -> fp32, 512 blocks
  mgemm_k<64,64,2><<<dim3(1024/64, M_/64), 128, 0, stream>>>(
      ycomb, outwb, outp, 2048, 1024, nullptr, nullptr, x, nullptr);
  // 13. layernorm -> d_out
  ln_k<<<M_, 256, 0, stream>>>(outp, ln_g, ln_b, out);
}

// Round 7
// 410.491 us; speedup vs baseline: 4.1226x; 1.0797x over previous
//
#include <hip/hip_runtime.h>
#include <math.h>

#define B_ 2
#define L_ 1024
#define DM_ 1024
#define STATE_ 16
#define CONV_ 4
#define DTR_ 8
#define INNER_ 2048
#define M_ (B_*L_)        /* 2048 rows (b,l) */
#define MD_ (B_*INNER_)   /* 4096 rows (b,c) */
#define NFFT_ 513
#define NFP_ 1152         /* 2*513=1026 padded to multiple of 128 */
#define NCH_ 32
#define CHL_ 32
#define SK_ 32            /* x_proj split-K factor */
#define KSL_ (2048/SK_)   /* 64 */

typedef unsigned short u16;
typedef __attribute__((ext_vector_type(8))) short short8;
typedef __attribute__((ext_vector_type(8))) __bf16 bf16x8;
typedef __attribute__((ext_vector_type(4))) float f32x4;

__device__ __forceinline__ float frcp_(float x) { return __builtin_amdgcn_rcpf(x); }
__device__ __forceinline__ float fexp_(float x) { return __expf(x); }
__device__ __forceinline__ float fsigm_(float x) { return frcp_(1.f + __expf(-x)); }
__device__ __forceinline__ float fsilu_(float x) { return x * frcp_(1.f + __expf(-x)); }
__device__ __forceinline__ float fsoftplus_(float v) {
  return (v > 20.f) ? v : __logf(1.f + __expf(v));
}
__device__ __forceinline__ u16 f2bf(float f) {
  union { float f; unsigned u; } v; v.f = f;
  unsigned r = v.u + 0x7fffu + ((v.u >> 16) & 1u);
  return (u16)(r >> 16);
}
__device__ __forceinline__ float bf2f(u16 h) {
  union { unsigned u; float f; } v; v.u = ((unsigned)h) << 16;
  return v.f;
}
__device__ __forceinline__ void gload16(const void* g, void* l) {
  __builtin_amdgcn_global_load_lds(
      (const __attribute__((address_space(1))) unsigned*)g,
      (__attribute__((address_space(3))) unsigned*)l, 16, 0, 0);
}
__device__ __forceinline__ f32x4 mfma_bf16(short8 a, short8 b, f32x4 c) {
  return __builtin_amdgcn_mfma_f32_16x16x32_bf16(
      __builtin_bit_cast(bf16x8, a), __builtin_bit_cast(bf16x8, b), c, 0, 0, 0);
}

// ---------------- fp32 -> bf16 conversion (4 sources, contiguous dst) -------
#define CVT_N0 2097152
#define CVT_N1 6291456
#define CVT_N2 14680064
#define CVT_NT 16777216
__global__ __launch_bounds__(256) void cvt4_k(
    const float* __restrict__ s0, const float* __restrict__ s1,
    const float* __restrict__ s2, const float* __restrict__ s3,
    u16* __restrict__ out)
{
  int i = (blockIdx.x*256 + threadIdx.x) * 4;
  const float* src; int off;
  if (i < CVT_N0)      { src = s0; off = 0; }
  else if (i < CVT_N1) { src = s1; off = CVT_N0; }
  else if (i < CVT_N2) { src = s2; off = CVT_N1; }
  else                 { src = s3; off = CVT_N2; }
  float4 v = *(const float4*)(src + (i - off));
  ushort4 o;
  o.x = f2bf(v.x); o.y = f2bf(v.y); o.z = f2bf(v.z); o.w = f2bf(v.w);
  *(ushort4*)(out + i) = o;
}

// ---------------- bf16 MFMA GEMM (templated tile, double-buffered) ----------
// C[m,n] = sum_k A[m,k]*Bt[n,k].  A: M x K bf16, Bt: N x K bf16, K%64==0.
// Wave sub-tile 64x32 (acc 4x2); waves = (TM/64)*(TN/32).
// EPI: 0 plain f32; 1 fusion gate (bf16); 2 residual add (f32);
//      3 spectral filter (bf16); 5 in_proj (f32 + transposed bf16 xt);
//      6 inv-DFT (bf16 transposed into ycat).
template<int TM, int TN, int EPI>
__global__ __launch_bounds__((TM/64)*(TN/32)*64) void mgemm_k(
    const u16* __restrict__ Ab, const u16* __restrict__ Bb,
    void* __restrict__ Cout, int K, int ldc,
    const float* __restrict__ aux0, u16* __restrict__ aux1,
    const float* __restrict__ aux2, const float* __restrict__ aux3)
{
  constexpr int WN   = TN/32;
  constexpr int NW   = (TM/64)*WN;
  constexpr int NTHR = NW*64;
  __shared__ __align__(16) u16 As[2][TM*64];
  __shared__ __align__(16) u16 Bs[2][TN*64];
  const int t = threadIdx.x;
  const int lane = t & 63;
  const int w = t >> 6;
  const int wm = w / WN, wn = w % WN;
  const int M0 = blockIdx.y * TM, N0 = blockIdx.x * TN;

  f32x4 acc[4][2] = {};

  auto stage = [&](int buf, int k0) {
    #pragma unroll
    for (int q = 0; q < TM*8/NTHR; q++) {
      int u = q*NTHR + t;
      int row = u >> 3, gpr = u & 7;
      int grp = gpr ^ (row & 7);        // XOR swizzle
      gload16(Ab + (size_t)(M0+row)*K + k0 + grp*8, &As[buf][u*8]);
    }
    #pragma unroll
    for (int q = 0; q < TN*8/NTHR; q++) {
      int u = q*NTHR + t;
      int row = u >> 3, gpr = u & 7;
      int grp = gpr ^ (row & 7);
      gload16(Bb + (size_t)(N0+row)*K + k0 + grp*8, &Bs[buf][u*8]);
    }
  };

  stage(0, 0);
  const int nk = K >> 6;
  for (int ks = 0; ks < nk; ks++) {
    const int buf = ks & 1;
    __syncthreads();                    // drain stage(buf); protect buf^1 overwrite
    if (ks + 1 < nk) stage(buf ^ 1, (ks + 1) << 6);
    const u16* Asb = As[buf];
    const u16* Bsb = Bs[buf];
    #pragma unroll
    for (int kk = 0; kk < 2; kk++) {
      const int quad = lane >> 4;
      const int grp = kk*4 + quad;
      short8 af[4], bf[2];
      #pragma unroll
      for (int i = 0; i < 4; i++) {
        int row = wm*64 + i*16 + (lane & 15);
        af[i] = *(const short8*)&Asb[(row*8 + (grp ^ (row & 7)))*8];
      }
      #pragma unroll
      for (int j = 0; j < 2; j++) {
        int row = wn*32 + j*16 + (lane & 15);
        bf[j] = *(const short8*)&Bsb[(row*8 + (grp ^ (row & 7)))*8];
      }
      #pragma unroll
      for (int i = 0; i < 4; i++)
        #pragma unroll
        for (int j = 0; j < 2; j++)
          acc[i][j] = mfma_bf16(af[i], bf[j], acc[i][j]);
    }
  }

  // C/D layout: col = lane&15, row = (lane>>4)*4 + r
  #pragma unroll
  for (int i = 0; i < 4; i++) {
    int mbase = M0 + wm*64 + i*16 + (lane >> 4)*4;
    #pragma unroll
    for (int j = 0; j < 2; j++) {
      int n = N0 + wn*32 + j*16 + (lane & 15);
      #pragma unroll
      for (int r = 0; r < 4; r++) {
        int m = mbase + r;
        float v = acc[i][j][r];
        if (EPI == 0) {
          ((float*)Cout)[(size_t)m*ldc + n] = v;
        } else if (EPI == 1) {          // fusion gate
          float g  = fsigm_(v + aux0[n]);
          float ys = bf2f(aux1[(size_t)m*4096 + n]);
          float yp = bf2f(aux1[(size_t)m*4096 + 2048 + n]);
          float z  = aux2[(size_t)m*4096 + 2048 + n];
          ((u16*)Cout)[(size_t)m*ldc + n] = f2bf((g*ys + (1.f-g)*yp)*fsilu_(z));
        } else if (EPI == 2) {          // residual add
          ((float*)Cout)[(size_t)m*ldc + n] = v + aux2[(size_t)m*ldc + n];
        } else if (EPI == 3) {          // spectral filter, complex pair via shfl
          float pv = __shfl_xor(v, 1, 64);
          int f = n >> 1;
          float outv = 0.f;
          if (f < NFFT_) {
            int c = m & (INNER_-1);
            float d  = fexp_(-aux2[c] * (float)f * (1.f/512.f));
            float wr = aux0[c*NFFT_+f]*d, wi = aux3[c*NFFT_+f]*d;
            float a = (n & 1) ? pv : v;
            float b = (n & 1) ? v : pv;
            outv = (n & 1) ? (a*wi + b*wr) : (a*wr - b*wi);
          }
          ((u16*)Cout)[(size_t)m*ldc + n] = f2bf(outv);
        } else if (EPI == 5) {          // in_proj: xz f32 + transposed bf16 xt
          ((float*)Cout)[(size_t)m*ldc + n] = v;
          if (n < 2048) {
            int b2 = m >> 10, l2 = m & 1023;
            aux1[((size_t)(b2*2048 + n) << 10) + l2] = f2bf(v);
          }
        } else {                        // 6: inv-DFT transposed into ycat
          int b2 = m >> 11, c2 = m & (INNER_-1);
          ((u16*)Cout)[((size_t)((b2 << 10) + n) << 12) + 2048 + c2] = f2bf(v);
        }
      }
    }
  }
}

// ---------------- x_proj split-K: part[sk][m][40] = xconv[m, sk*64:+64] @ W^T ----
__global__ __launch_bounds__(256) void xproj_k(
    const float* __restrict__ xconv, const float* __restrict__ W,
    float* __restrict__ part)
{
  __shared__ float Bs[40][KSL_+4];
  const int sk = blockIdx.x, mt = blockIdx.y;
  const int k0 = sk*KSL_;
  for (int i = threadIdx.x; i < 40*KSL_; i += 256) {
    int n = i >> 6, k = i & (KSL_-1);
    Bs[n][k] = W[(size_t)n*2048 + k0 + k];
  }
  __syncthreads();
  const int m = mt*256 + threadIdx.x;
  const float* arow = xconv + (size_t)m*2048 + k0;
  float acc[40];
  #pragma unroll
  for (int j=0;j<40;j++) acc[j]=0.f;
  for (int k = 0; k < KSL_; k += 4) {
    float4 a = *(const float4*)(arow + k);
    #pragma unroll
    for (int j = 0; j < 40; j++) {
      float4 b = *(const float4*)&Bs[j][k];
      acc[j] += a.x*b.x + a.y*b.y + a.z*b.z + a.w*b.w;
    }
  }
  float* o = part + ((size_t)sk*M_ + m)*40;
  #pragma unroll
  for (int j = 0; j < 10; j++)
    *(float4*)(o + j*4) = make_float4(acc[j*4], acc[j*4+1], acc[j*4+2], acc[j*4+3]);
}

__global__ __launch_bounds__(256) void xpred_k(const float* __restrict__ part,
                                               float* __restrict__ xdbc)
{
  int i = blockIdx.x*256 + threadIdx.x;   // 81920 total
  float s = 0.f;
  #pragma unroll
  for (int sk = 0; sk < SK_; sk++) s += part[(size_t)sk*81920 + i];
  xdbc[i] = s;
}

// ---------------- depthwise causal conv(4) + silu, 8 l per thread ----------
__global__ __launch_bounds__(256) void conv_silu_k(
    const float* __restrict__ xz, const float* __restrict__ cw,
    const float* __restrict__ cb, float* __restrict__ xc)
{
  int idx = blockIdx.x*256 + threadIdx.x;   // 524288 total
  int c = idx & (INNER_-1);
  int g = idx >> 11;                        // 0..255
  int b = g >> 7;
  int lb = (g & 127) * 8;
  float w0=cw[c*4+0], w1=cw[c*4+1], w2=cw[c*4+2], w3=cw[c*4+3];
  float bias = cb[c];
  float v[11];
  #pragma unroll
  for (int j = 0; j < 11; j++) {
    int l = lb - 3 + j;
    v[j] = (l >= 0) ? xz[((size_t)((b << 10) + l))*4096 + c] : 0.f;
  }
  #pragma unroll
  for (int j = 0; j < 8; j++) {
    float s = bias + w0*v[j] + w1*v[j+1] + w2*v[j+2] + w3*v[j+3];
    xc[((size_t)((b << 10) + lb + j))*INNER_ + c] = fsilu_(s);
  }
}

// ---------------- SSM chunked scan (prefetched) ----------------
// Pq layout per (b,ch,e): [0..15] = P (chunk transfer), [16..31] = q, then
// scan2 overwrites q-slot with h_in for that chunk.
__global__ __launch_bounds__(256) void scan1_k(
    const float* __restrict__ xdbc, const float* __restrict__ xconv,
    const float* __restrict__ A_log, const float* __restrict__ dtw,
    const float* __restrict__ dtb, float* __restrict__ Pq)
{
  int idx = blockIdx.x*256 + threadIdx.x;   // (b*NCH+ch)*INNER + e
  int e  = idx & (INNER_-1);
  int bc = idx >> 11;
  int ch = bc & (NCH_-1);
  int b  = bc >> 5;
  float A[STATE_];
  #pragma unroll
  for (int s=0;s<STATE_;s++) A[s] = -fexp_(A_log[e*STATE_+s]);
  float w[DTR_];
  #pragma unroll
  for (int r=0;r<DTR_;r++) w[r] = dtw[e*DTR_+r];
  float bias = dtb[e];
  float h[STATE_] = {};
  float sdt = 0.f;
  int mbase = b*L_ + ch*CHL_;
  // current-step inputs
  float dtx[DTR_], Bv[STATE_], xcv;
  {
    const float* row = xdbc + (size_t)mbase*40;
    #pragma unroll
    for (int r=0;r<DTR_;r++) dtx[r] = row[r];
    #pragma unroll
    for (int s=0;s<STATE_;s++) Bv[s] = row[8+s];
    xcv = xconv[(size_t)mbase*INNER_ + e];
  }
  for (int l=0;l<CHL_;l++) {
    float ndtx[DTR_], nBv[STATE_], nxcv = 0.f;
    if (l+1 < CHL_) {                 // prefetch next step
      const float* nrow = xdbc + (size_t)(mbase+l+1)*40;
      #pragma unroll
      for (int r=0;r<DTR_;r++) ndtx[r] = nrow[r];
      #pragma unroll
      for (int s=0;s<STATE_;s++) nBv[s] = nrow[8+s];
      nxcv = xconv[(size_t)(mbase+l+1)*INNER_ + e];
    } else {
      #pragma unroll
      for (int r=0;r<DTR_;r++) ndtx[r] = 0.f;
      #pragma unroll
      for (int s=0;s<STATE_;s++) nBv[s] = 0.f;
    }
    float v = bias;
    #pragma unroll
    for (int r=0;r<DTR_;r++) v += dtx[r]*w[r];
    float dt = fsoftplus_(v);
    sdt += dt;
    float dx = dt * xcv;
    #pragma unroll
    for (int s=0;s<STATE_;s++) {
      float dA = fexp_(dt*A[s]);
      h[s] = dA*h[s] + dx*Bv[s];
    }
    #pragma unroll
    for (int r=0;r<DTR_;r++) dtx[r] = ndtx[r];
    #pragma unroll
    for (int s=0;s<STATE_;s++) Bv[s] = nBv[s];
    xcv = nxcv;
  }
  float* o = Pq + (size_t)idx*32;
  #pragma unroll
  for (int s=0;s<STATE_;s++) { o[s] = fexp_(A[s]*sdt); o[16+s] = h[s]; }
}

// combine chunks, parallel over (b,e,s); h_in written into the q slot
__global__ __launch_bounds__(256) void scan2_k(float* __restrict__ Pq)
{
  int idx = blockIdx.x*256 + threadIdx.x;   // b*(INNER*16) + e*16 + s ; 65536
  int s = idx & 15;
  int e = (idx >> 4) & (INNER_-1);
  int b = idx >> 15;
  float h = 0.f;
  for (int ch = 0; ch < NCH_; ch++) {
    size_t base = ((size_t)(b*NCH_+ch)*INNER_ + e)*32;
    float p = Pq[base + s];
    float q = Pq[base + 16 + s];
    Pq[base + 16 + s] = h;
    h = p*h + q;
  }
}

__global__ __launch_bounds__(256) void scan3_k(
    const float* __restrict__ xdbc, const float* __restrict__ xconv,
    const float* __restrict__ A_log, const float* __restrict__ dtw,
    const float* __restrict__ dtb, const float* __restrict__ Dp,
    const float* __restrict__ Pq, u16* __restrict__ ycat)
{
  int idx = blockIdx.x*256 + threadIdx.x;
  int e  = idx & (INNER_-1);
  int bc = idx >> 11;
  int ch = bc & (NCH_-1);
  int b  = bc >> 5;
  float A[STATE_];
  #pragma unroll
  for (int s=0;s<STATE_;s++) A[s] = -fexp_(A_log[e*STATE_+s]);
  float w[DTR_];
  #pragma unroll
  for (int r=0;r<DTR_;r++) w[r] = dtw[e*DTR_+r];
  float bias = dtb[e];
  float Dv = Dp[e];
  float h[STATE_];
  const float* hi = Pq + (size_t)idx*32 + 16;
  #pragma unroll
  for (int s=0;s<STATE_;s++) h[s] = hi[s];
  int mbase = b*L_ + ch*CHL_;
  float dtx[DTR_], Bv[STATE_], Cv[STATE_], xcv;
  {
    const float* row = xdbc + (size_t)mbase*40;
    #pragma unroll
    for (int r=0;r<DTR_;r++) dtx[r] = row[r];
    #pragma unroll
    for (int s=0;s<STATE_;s++) { Bv[s] = row[8+s]; Cv[s] = row[24+s]; }
    xcv = xconv[(size_t)mbase*INNER_ + e];
  }
  for (int l=0;l<CHL_;l++) {
    float ndtx[DTR_], nBv[STATE_], nCv[STATE_], nxcv = 0.f;
    if (l+1 < CHL_) {
      const float* nrow = xdbc + (size_t)(mbase+l+1)*40;
      #pragma unroll
      for (int r=0;r<DTR_;r++) ndtx[r] = nrow[r];
      #pragma unroll
      for (int s=0;s<STATE_;s++) { nBv[s] = nrow[8+s]; nCv[s] = nrow[24+s]; }
      nxcv = xconv[(size_t)(mbase+l+1)*INNER_ + e];
    } else {
      #pragma unroll
      for (int r=0;r<DTR_;r++) ndtx[r] = 0.f;
      #pragma unroll
      for (int s=0;s<STATE_;s++) { nBv[s] = 0.f; nCv[s] = 0.f; }
    }
    float v = bias;
    #pragma unroll
    for (int r=0;r<DTR_;r++) v += dtx[r]*w[r];
    float dt = fsoftplus_(v);
    float dx = dt * xcv;
    float y = 0.f;
    #pragma unroll
    for (int s=0;s<STATE_;s++) {
      float dA = fexp_(dt*A[s]);
      h[s] = dA*h[s] + dx*Bv[s];
      y += h[s]*Cv[s];
    }
    ycat[(size_t)(mbase+l)*4096 + e] = f2bf(y + xcv*Dv);
    #pragma unroll
    for (int r=0;r<DTR_;r++) dtx[r] = ndtx[r];
    #pragma unroll
    for (int s=0;s<STATE_;s++) { Bv[s] = nBv[s]; Cv[s] = nCv[s]; }
    xcv = nxcv;
  }
}

// ---------------- DFT matrix generation (bf16, K-contiguous) ----------------
__global__ __launch_bounds__(256) void genWdftb_k(u16* __restrict__ W) {
  int idx = blockIdx.x*256 + threadIdx.x;  // col*1024 + l ; col < NFP_
  int l = idx & (L_-1);
  int col = idx >> 10;
  float v = 0.f;
  int f = col >> 1;
  if (f < NFFT_) {
    int ph = (l*f) & (L_-1);
    float th = (float)ph * (6.283185307179586f / (float)L_);
    v = (col & 1) ? -__sinf(th) : __cosf(th);
  }
  W[idx] = f2bf(v);
}

__global__ __launch_bounds__(256) void genWinvb_k(u16* __restrict__ W) {
  int idx = blockIdx.x*256 + threadIdx.x;  // l*NFP_ + r
  int r = idx % NFP_;
  int l = idx / NFP_;
  int f = r >> 1;
  float v = 0.f;
  if (f < NFFT_) {
    bool edge = (f == 0) || (f == 512);
    float sc = (edge ? 1.f : 2.f) / (float)L_;
    int ph = (f*l) & (L_-1);
    float th = (float)ph * (6.283185307179586f / (float)L_);
    if (r & 1) v = edge ? 0.f : -sc*__sinf(th);
    else       v = sc*__cosf(th);
  }
  W[idx] = f2bf(v);
}

// ---------------- layernorm ----------------
__global__ __launch_bounds__(256) void ln_k(const float* __restrict__ inp,
    const float* __restrict__ gma, const float* __restrict__ bta,
    float* __restrict__ out)
{
  int m = blockIdx.x;
  const float* row = inp + (size_t)m*DM_;
  float s=0.f, s2=0.f;
  float v[4];
  #pragma unroll
  for (int j=0;j<4;j++) {
    v[j] = row[threadIdx.x + j*256];
    s += v[j]; s2 += v[j]*v[j];
  }
  #pragma unroll
  for (int off=32; off>=1; off>>=1) {
    s  += __shfl_down(s, off);
    s2 += __shfl_down(s2, off);
  }
  __shared__ float rs[4], rs2[4], stats[2];
  int wid = threadIdx.x >> 6;
  if ((threadIdx.x & 63) == 0) { rs[wid]=s; rs2[wid]=s2; }
  __syncthreads();
  if (threadIdx.x == 0) {
    float ts  = rs[0]+rs[1]+rs[2]+rs[3];
    float ts2 = rs2[0]+rs2[1]+rs2[2]+rs2[3];
    float mu  = ts/(float)DM_;
    float var = ts2/(float)DM_ - mu*mu;
    stats[0] = mu; stats[1] = rsqrtf(var + 1e-5f);
  }
  __syncthreads();
  float mu = stats[0], rstd = stats[1];
  #pragma unroll
  for (int j=0;j<4;j++) {
    int n = threadIdx.x + j*256;
    out[(size_t)m*DM_ + n] = (v[j]-mu)*rstd*gma[n] + bta[n];
  }
}

extern "C" void kernel_launch(void* const* d_in, const int* in_sizes, int n_in,
                              void* d_out, int out_size, void* d_ws, size_t ws_size,
                              hipStream_t stream)
{
  const float* x       = (const float*)d_in[0];
  const float* in_w    = (const float*)d_in[1];
  const float* conv_w  = (const float*)d_in[2];
  const float* conv_b  = (const float*)d_in[3];
  const float* A_log   = (const float*)d_in[4];
  const float* Dp      = (const float*)d_in[5];
  const float* xproj_w = (const float*)d_in[6];
  const float* dt_w    = (const float*)d_in[7];
  const float* dt_b    = (const float*)d_in[8];
  const float* f_re    = (const float*)d_in[9];
  const float* f_im    = (const float*)d_in[10];
  const float* s_dec   = (const float*)d_in[11];
  const float* fus_w   = (const float*)d_in[12];
  const float* fus_b   = (const float*)d_in[13];
  const float* out_w   = (const float*)d_in[14];
  const float* ln_g    = (const float*)d_in[15];
  const float* ln_b    = (const float*)d_in[16];
  float* out = (float*)d_out;

  // ---- workspace carve (fp32 region then bf16 region), ~138 MB total ----
  float* ws    = (float*)d_ws;
  float* xz    = ws;                       // 8388608  (M x 4096)
  float* xconv = xz    + 8388608;          // 4194304  (M x 2048), reused as outp
  float* xdbc  = xconv + 4194304;          // 81920    (M x 40)
  float* Pq    = xdbc  + 81920;            // 4194304  (B*NCH*INNER x 32), holds h_in too
  u16* ub      = (u16*)(Pq + 4194304);
  u16* xb      = ub;                       // 2097152   x bf16
  u16* inwb    = xb    + 2097152;          // 4194304   in_w bf16
  u16* fuswb   = inwb  + 4194304;          // 8388608   fus_w bf16
  u16* outwb   = fuswb + 8388608;          // 2097152   out_w bf16
  u16* xt      = outwb + 2097152;          // 4194304   x_inner^T bf16; reused as ycomb
  u16* Wb      = xt    + 4194304;          // 1179648   Wdft then Winv
  u16* XFb     = Wb    + 1179648;          // 4718592   (MD x NFP) bf16
  u16* ycat    = XFb   + 4718592;          // 8388608   (M x 4096) bf16
  u16* ycomb   = xt;
  float* outp  = xconv;
  float* part  = (float*)ycat;             // 2.6M floats, dead before scan3 writes ycat

  // 0. convert GEMM operands to bf16 (xb,inwb,fuswb,outwb are contiguous)
  cvt4_k<<<CVT_NT/1024, 256, 0, stream>>>(x, in_w, fus_w, out_w, xb);

  // 1. xz = x @ in_proj_w^T (2048 x 4096 x 1024); epilogue also writes xt (bf16 transposed)
  mgemm_k<128,128,5><<<dim3(4096/128, M_/128), 512, 0, stream>>>(
      xb, inwb, xz, 1024, 4096, nullptr, xt, nullptr, nullptr);
  // 2. depthwise conv + silu (8 l per thread)
  conv_silu_k<<<(M_*INNER_/8)/256, 256, 0, stream>>>(xz, conv_w, conv_b, xconv);
  // 3. x_dbc = x_conv @ x_proj_w^T  (2048 x 40 x 2048) split-K fp32
  xproj_k<<<dim3(SK_, M_/256), 256, 0, stream>>>(xconv, xproj_w, part);
  xpred_k<<<(M_*40)/256, 256, 0, stream>>>(part, xdbc);
  // 4-6. chunked SSM scan -> y_cat[:, :2048] (bf16)
  scan1_k<<<(B_*NCH_*INNER_)/256, 256, 0, stream>>>(xdbc, xconv, A_log, dt_w, dt_b, Pq);
  scan2_k<<<(B_*INNER_*STATE_)/256, 256, 0, stream>>>(Pq);
  scan3_k<<<(B_*NCH_*INNER_)/256, 256, 0, stream>>>(xdbc, xconv, A_log, dt_w, dt_b, Dp, Pq, ycat);
  // 7. forward DFT + fused spectral filter: XFb = filt(xt @ Wdft), 576 blocks
  genWdftb_k<<<(NFP_*1024)/256, 256, 0, stream>>>(Wb);
  mgemm_k<128,64,3><<<dim3(NFP_/64, MD_/128), 256, 0, stream>>>(
      xt, Wb, XFb, 1024, NFP_, f_re, nullptr, s_dec, f_im);
  // 8. inverse DFT (4096 x 1024 x 1152); epilogue writes transposed into ycat[:,2048:]
  genWinvb_k<<<(NFP_*1024)/256, 256, 0, stream>>>(Wb);
  mgemm_k<128,64,6><<<dim3(1024/64, MD_/128), 256, 0, stream>>>(
      XFb, Wb, ycat, NFP_, 0, nullptr, nullptr, nullptr, nullptr);
  // 9. fusion GEMM + gate epilogue (2048 x 2048 x 4096) -> ycomb bf16, 512 blocks
  mgemm_k<128,64,1><<<dim3(2048/64, M_/128), 256, 0, stream>>>(
      ycat, fuswb, ycomb, 4096, 2048, fus_b, ycat, xz, nullptr);
  // 10. out proj + residual (2048 x 1024 x 2048) -> fp32, 512 blocks
  mgemm_k<64,64,2><<<dim3(1024/64, M_/64), 128, 0, stream>>>(
      ycomb, outwb, outp, 2048, 1024, nullptr, nullptr, x, nullptr);
  // 11. layernorm -> d_out
  ln_k<<<M_, 256, 0, stream>>>(outp, ln_g, ln_b, out);
}